// Round 9
// baseline (247.389 us; speedup 1.0000x reference)
//
#include <hip/hip_runtime.h>

#define DEVINL __device__ __forceinline__

// Problem constants
#define BB 4
#define SS 4096
#define HIDD 1024
#define HH 16
#define DH 64
#define NQKV 3072
#define MM (BB * SS)  // 16384

typedef __attribute__((ext_vector_type(8))) short bf16x8_t;
typedef __attribute__((ext_vector_type(4))) float f32x4_t;
typedef __attribute__((ext_vector_type(16))) float f32x16_t;

typedef __attribute__((address_space(1))) const void GV;
typedef __attribute__((address_space(3))) void LV;

DEVINL void gload16(const void* g, void* l) {
  // async global->LDS, 16B/lane; LDS dest = wave-uniform base + lane*16
  __builtin_amdgcn_global_load_lds((GV*)g, (LV*)l, 16, 0, 0);
}

DEVINL float bf2f(ushort u) {
  union { unsigned int i; float f; } v;
  v.i = ((unsigned int)u) << 16;
  return v.f;
}
DEVINL ushort f2bf(float f) {
  unsigned int u = __float_as_uint(f);
  u = (u + 0x7fffu + ((u >> 16) & 1u)) >> 16;
  return (ushort)u;
}

// ---------------- fp32 -> bf16 convert (4 elems/thread) ----------------
__global__ __launch_bounds__(256) void k_f2bf(const float* __restrict__ src,
                                              ushort* __restrict__ dst, int n4) {
  int i = blockIdx.x * 256 + threadIdx.x;
  if (i >= n4) return;
  float4 v = ((const float4*)src)[i];
  ushort4 o;
  o.x = f2bf(v.x); o.y = f2bf(v.y); o.z = f2bf(v.z); o.w = f2bf(v.w);
  ((ushort4*)dst)[i] = o;
}

// ------- 8-phase 256x256 bf16 GEMM with 32x32x16 MFMA fragments -------
// 8 waves (2M x 4N); per wave 128x64 out = 4x2 frags of 32x32 (f32x16 acc).
// BK=64 = 4 ksteps of 16. Per 4-phase group (one K-tile): B preloaded at ph0
// (2x4 frags, 8 ds_read_b128), A per phase (4 reads), 8 MFMA per phase.
// 2 LDS slots per operand (128 KiB); counted vmcnt(4) at ph3/ph7 only.
// Runtime J loop (small body, no I-cache blowup); tail stages clamp to the
// last valid K-tile (written to never-again-read slots — no branches).
// Swizzle: 16B chunk ^= (row&7) on pre-swizzled global source and frag reads.
// MODE 1: fp32 natural C (+bias). MODE 2: QKV split epilogue.
template <int MODE, int NDIM, int KDIM>
__global__ __launch_bounds__(512, 2) void k_gemm8p(
    const ushort* __restrict__ A, const ushort* __restrict__ B,
    const float* __restrict__ bias, void* __restrict__ Cv,
    ushort* __restrict__ qT, ushort* __restrict__ vbuf) {
  __shared__ ushort As0[256 * 64];
  __shared__ ushort As1[256 * 64];
  __shared__ ushort Bs0[256 * 64];
  __shared__ ushort Bs1[256 * 64];
  constexpr int NT = KDIM >> 6;
  constexpr int NJ = NT >> 1;
  const int t = threadIdx.x;
  const int m0 = blockIdx.x * 256, n0 = blockIdx.y * 256;
  const int lane = t & 63, wid = t >> 6;
  const int wm = wid >> 2, wn = wid & 3;   // 2M x 4N waves
  const int l31 = lane & 31, lhi = lane >> 5;
  const int srow = t >> 3;                        // 0..63 (row within 64-row call)
  const int schunk = ((t & 7) ^ (srow & 7)) * 8;  // pre-swizzled 16B chunk
  // per-thread staging bases
  const ushort* Ab = A + (size_t)(m0 + srow) * KDIM + schunk;
  const ushort* Bb = B + (size_t)(n0 + srow) * KDIM + schunk;

  f32x16_t acc[4][2] = {};
  bf16x8_t af32[4], bf32[2][4];

  // stage half-tile hf of the K-tile at ushort-offset ko into LDS slot ls_
#define STG(ls_, gb_, ko, hf)                                               \
  {                                                                         \
    gload16((gb_) + (size_t)((hf) * 128) * KDIM + (ko),                     \
            (ls_) + ((hf) * 128 + wid * 8) * 64);                           \
    gload16((gb_) + (size_t)((hf) * 128 + 64) * KDIM + (ko),                \
            (ls_) + ((hf) * 128 + wid * 8 + 64) * 64);                      \
  }

  // A frags for kstep k_: row = wm*128 + mf*32 + l31, k-chunk = k_*2 + lhi
#define LDA(as_, k_)                                                        \
  _Pragma("unroll") for (int mf = 0; mf < 4; ++mf) {                        \
    int r = wm * 128 + mf * 32 + l31;                                       \
    af32[mf] = *(const bf16x8_t*)&(as_)[r * 64 + ((((k_)*2 + lhi) ^ (r & 7)) * 8)]; \
  }

  // all B frags for this K-tile: col = wn*64 + nf*32 + l31, ksteps 0..3
#define LDB(bs_)                                                            \
  _Pragma("unroll") for (int nf = 0; nf < 2; ++nf)                          \
  _Pragma("unroll") for (int k_ = 0; k_ < 4; ++k_) {                        \
    int r = wn * 64 + nf * 32 + l31;                                        \
    bf32[nf][k_] = *(const bf16x8_t*)&(bs_)[r * 64 + (((k_*2 + lhi) ^ (r & 7)) * 8)]; \
  }

#define MMA(k_)                                                             \
  _Pragma("unroll") for (int mf = 0; mf < 4; ++mf)                          \
  _Pragma("unroll") for (int nf = 0; nf < 2; ++nf)                          \
    acc[mf][nf] = __builtin_amdgcn_mfma_f32_32x32x16_bf16(                  \
        af32[mf], bf32[nf][k_], acc[mf][nf], 0, 0, 0);

#define BAR1                                                                \
  __builtin_amdgcn_s_barrier();                                             \
  __builtin_amdgcn_s_setprio(1);

#define BAR2                                                                \
  __builtin_amdgcn_s_setprio(0);                                            \
  __builtin_amdgcn_s_barrier();

#define BAR2VM                                                              \
  __builtin_amdgcn_s_setprio(0);                                            \
  asm volatile("s_waitcnt vmcnt(4)" ::: "memory");                          \
  __builtin_amdgcn_s_barrier();                                             \
  __builtin_amdgcn_sched_barrier(0);

  // prologue: B(0), A(0), B(1) fully staged
  STG(Bs0, Bb, 0, 0); STG(Bs0, Bb, 0, 1);
  STG(As0, Ab, 0, 0); STG(As0, Ab, 0, 1);
  STG(Bs1, Bb, 64, 0); STG(Bs1, Bb, 64, 1);
  asm volatile("s_waitcnt vmcnt(4)" ::: "memory");
  __builtin_amdgcn_s_barrier();
  __builtin_amdgcn_sched_barrier(0);

  for (int J = 0; J < NJ; ++J) {
    const int o1 = (2 * J + 1) * 64;                              // T1 (A)
    const int o2 = (2 * J + 2 < NT ? 2 * J + 2 : NT - 1) * 64;    // T0+2 (clamped)
    const int o3 = (2 * J + 3 < NT ? 2 * J + 3 : NT - 1) * 64;    // T1+2 (clamped)
    // ph0..3: compute K-tile T0 from As0/Bs0
    LDA(As0, 0); LDB(Bs0); STG(As1, Ab, o1, 0);
    BAR1; MMA(0); BAR2;
    LDA(As0, 1); STG(As1, Ab, o1, 1);
    BAR1; MMA(1); BAR2;
    LDA(As0, 2); STG(Bs0, Bb, o2, 0);
    BAR1; MMA(2); BAR2;
    LDA(As0, 3); STG(Bs0, Bb, o2, 1);
    BAR1; MMA(3); BAR2VM;
    // ph4..7: compute K-tile T1 from As1/Bs1
    LDA(As1, 0); LDB(Bs1); STG(As0, Ab, o2, 0);
    BAR1; MMA(0); BAR2;
    LDA(As1, 1); STG(As0, Ab, o2, 1);
    BAR1; MMA(1); BAR2;
    LDA(As1, 2); STG(Bs1, Bb, o3, 0);
    BAR1; MMA(2); BAR2;
    LDA(As1, 3); STG(Bs1, Bb, o3, 1);
    BAR1; MMA(3); BAR2VM;
  }
#undef STG
#undef LDA
#undef LDB
#undef MMA
#undef BAR1
#undef BAR2
#undef BAR2VM

  // epilogue: 32x32 C/D mapping col=lane&31, row=(reg&3)+8*(reg>>2)+4*(lane>>5)
#pragma unroll
  for (int nf = 0; nf < 2; ++nf) {
    int col = n0 + wn * 64 + nf * 32 + l31;
    float bv = bias[col];
#pragma unroll
    for (int mf = 0; mf < 4; ++mf) {
#pragma unroll
      for (int rg = 0; rg < 4; ++rg) {
        int row = m0 + wm * 128 + mf * 32 + rg * 8 + lhi * 4;
        if (MODE == 1) {
#pragma unroll
          for (int j = 0; j < 4; ++j)
            ((float*)Cv)[(size_t)(row + j) * NDIM + col] = acc[mf][nf][rg * 4 + j] + bv;
        } else {
          ushort4 o;
          o.x = f2bf(acc[mf][nf][rg * 4 + 0] + bv);
          o.y = f2bf(acc[mf][nf][rg * 4 + 1] + bv);
          o.z = f2bf(acc[mf][nf][rg * 4 + 2] + bv);
          o.w = f2bf(acc[mf][nf][rg * 4 + 3] + bv);
          if (col < 2048) {
            int tt = col >> 10;           // 0=Q, 1=K
            int hh = (col >> 6) & 15;
            int d = col & 63;
            int b = row >> 12;
            int s = row & 4095;
            size_t off = ((((size_t)tt * BB + b) * HH + hh) * 64 + d) * SS + s;
            *(ushort4*)&qT[off] = o;     // 4 consecutive s
          } else {
            int c = col - 2048;
            vbuf[(size_t)(row + 0) * HIDD + c] = o.x;
            vbuf[(size_t)(row + 1) * HIDD + c] = o.y;
            vbuf[(size_t)(row + 2) * HIDD + c] = o.z;
            vbuf[(size_t)(row + 3) * HIDD + c] = o.w;
          }
        }
      }
    }
  }
}

// ------- gram eighth + fused sumsq partials -------
// grid (64 bh, 8 p): 512 s per block. 3-buffer counted-vmcnt staging.
// Partials to d_out scratch: Wp8[bh*8+p][64][64] f32, sq8/sk8[bh*8+p][64].
__global__ __launch_bounds__(256) void k_gram(const ushort* __restrict__ qT,
                                              float* __restrict__ Wp8,
                                              float* __restrict__ sq8,
                                              float* __restrict__ sk8) {
  __shared__ ushort Qs[3][64 * 64];
  __shared__ ushort Ks[3][64 * 64];
  const int bh = blockIdx.x, p = blockIdx.y;
  const ushort* Qp = qT + (size_t)bh * 64 * SS + p * 512;
  const ushort* Kp = qT + (size_t)(BB * HH + bh) * 64 * SS + p * 512;
  const int t = threadIdx.x;
  const int lane = t & 63, w = t >> 6;
  const int fr = lane & 15, g = lane >> 4;
  const int rsub = lane >> 3;
  const int gcol = ((lane & 7) ^ rsub) * 8;

  f32x4_t acc[4] = {};
  float sqa = 0.f, ska = 0.f;

#define STGG(b_, sc_)                                                       \
  _Pragma("unroll") for (int i = 0; i < 2; ++i) {                           \
    int rg = w * 2 + i;                                                     \
    int row = rg * 8 + rsub;                                                \
    gload16(&Qp[(size_t)row * SS + (sc_) * 64 + gcol], &Qs[b_][rg * 512]);  \
    gload16(&Kp[(size_t)row * SS + (sc_) * 64 + gcol], &Ks[b_][rg * 512]);  \
  }

#define GCOMP(bc)                                                           \
  {                                                                         \
    bf16x8_t af[2], bq[4][2];                                               \
    _Pragma("unroll") for (int kk = 0; kk < 2; ++kk) {                      \
      int r = w * 16 + fr;                                                  \
      af[kk] = *(const bf16x8_t*)&Qs[bc][r * 64 + (((kk * 4 + g) ^ (r & 7)) * 8)]; \
    }                                                                       \
    _Pragma("unroll") for (int ni = 0; ni < 4; ++ni)                        \
    _Pragma("unroll") for (int kk = 0; kk < 2; ++kk) {                      \
      int r2 = ni * 16 + fr;                                                \
      bq[ni][kk] = *(const bf16x8_t*)&Ks[bc][r2 * 64 + (((kk * 4 + g) ^ (r2 & 7)) * 8)]; \
    }                                                                       \
    _Pragma("unroll") for (int kk = 0; kk < 2; ++kk)                        \
    _Pragma("unroll") for (int ni = 0; ni < 4; ++ni)                        \
      acc[ni] = __builtin_amdgcn_mfma_f32_16x16x32_bf16(af[kk], bq[ni][kk], acc[ni], 0, 0, 0); \
    _Pragma("unroll") for (int kk = 0; kk < 2; ++kk)                        \
    _Pragma("unroll") for (int e = 0; e < 8; ++e) {                         \
      float fq = bf2f((ushort)af[kk][e]);                                   \
      sqa += fq * fq;                                                       \
    }                                                                       \
    _Pragma("unroll") for (int ni = 0; ni < 4; ++ni)                        \
      if (ni == w)                                                          \
        _Pragma("unroll") for (int kk = 0; kk < 2; ++kk)                    \
        _Pragma("unroll") for (int e = 0; e < 8; ++e) {                     \
          float fk = bf2f((ushort)bq[ni][kk][e]);                           \
          ska += fk * fk;                                                   \
        }                                                                   \
  }

#define GWAIT(n_)                                                           \
  asm volatile("s_waitcnt vmcnt(" #n_ ")" ::: "memory");                    \
  __builtin_amdgcn_s_barrier();                                             \
  __builtin_amdgcn_sched_barrier(0);

  STGG(0, 0);
  STGG(1, 1);
  for (int sc = 0; sc < 6; ++sc) {
    STGG((sc + 2) % 3, sc + 2);
    GWAIT(8);
    GCOMP(sc % 3);
    __builtin_amdgcn_s_barrier();
  }
  GWAIT(4); GCOMP(0); __builtin_amdgcn_s_barrier();  // sc=6 -> buf 0
  GWAIT(0); GCOMP(1);                                 // sc=7 -> buf 1
#undef STGG
#undef GCOMP
#undef GWAIT

  // reduce per-row sumsq over the 4 g-lanes; write partials
  sqa += __shfl_xor(sqa, 16, 64); sqa += __shfl_xor(sqa, 32, 64);
  ska += __shfl_xor(ska, 16, 64); ska += __shfl_xor(ska, 32, 64);
  const int bp = bh * 8 + p;
  if (g == 0) {
    sq8[bp * 64 + w * 16 + fr] = sqa;
    sk8[bp * 64 + w * 16 + fr] = ska;
  }
  float* wp = Wp8 + (size_t)bp * 4096;
#pragma unroll
  for (int ni = 0; ni < 4; ++ni)
#pragma unroll
    for (int j = 0; j < 4; ++j)
      wp[(w * 16 + g * 4 + j) * 64 + ni * 16 + fr] = acc[ni][j];
}

// ------- smx: combine partials, scale, softmax -> bf16 attnb[bh][64][72] ----
__global__ __launch_bounds__(256) void k_smx(const float* __restrict__ Wp8,
                                             const float* __restrict__ sq8,
                                             const float* __restrict__ sk8,
                                             const float* __restrict__ temperature,
                                             ushort* __restrict__ attnb) {
  __shared__ float attnf[64][65];
  __shared__ float iqL[64], ikL[64], invs[64];
  const int bh = blockIdx.x, h = bh & 15;
  const int t = threadIdx.x;
  if (t < 64) {
    float sq = 0.f, sk = 0.f;
#pragma unroll
    for (int p = 0; p < 8; ++p) {
      sq += sq8[(bh * 8 + p) * 64 + t];
      sk += sk8[(bh * 8 + p) * 64 + t];
    }
    iqL[t] = 1.0f / fmaxf(sqrtf(sq), 1e-12f);
    ikL[t] = 1.0f / fmaxf(sqrtf(sk), 1e-12f);
  }
  __syncthreads();
  float tscale = temperature[h] * (1.0f / 32.0f);
  for (int idx = t; idx < 4096; idx += 256) {
    int d = idx >> 6, e = idx & 63;
    float s = 0.f;
#pragma unroll
    for (int p = 0; p < 8; ++p) s += Wp8[(size_t)(bh * 8 + p) * 4096 + idx];
    attnf[d][e] = s * iqL[d] * ikL[e] * tscale;
  }
  __syncthreads();
  if (t < 64) {
    float m = -1e30f;
#pragma unroll 8
    for (int e = 0; e < 64; ++e) m = fmaxf(m, attnf[t][e]);
    float sum = 0.f;
#pragma unroll 8
    for (int e = 0; e < 64; ++e) {
      float v = __expf(attnf[t][e] - m);
      attnf[t][e] = v;
      sum += v;
    }
    invs[t] = 1.0f / sum;
  }
  __syncthreads();
  for (int idx = t; idx < 4096; idx += 256) {
    int d = idx >> 6, e = idx & 63;
    attnb[(size_t)bh * 4608 + d * 72 + e] = f2bf(attnf[d][e] * invs[d]);
  }
}

// ---------------- PV (MFMA): out[s][d] = sum_e V[s,e] * attn[d,e] ----------
// grid (64 bh, 8 p): 512 s-rows per block, 3-buffer counted-vmcnt staging.
__global__ __launch_bounds__(256) void k_pv(const ushort* __restrict__ vbuf,
                                            const ushort* __restrict__ attnb,
                                            ushort* __restrict__ attnout) {
  __shared__ ushort Vs[3][64 * 64];
  const int bh = blockIdx.x, p = blockIdx.y;
  const int b = bh >> 4, h = bh & 15;
  const int t = threadIdx.x;
  const int lane = t & 63, w = t >> 6;
  const int fr = lane & 15, g = lane >> 4;
  const int rsub = lane >> 3;
  const int gcol = ((lane & 7) ^ rsub) * 8;

  // B-frags straight from global attnb (L2-hot)
  bf16x8_t bfg[4][2];
#pragma unroll
  for (int ni = 0; ni < 4; ++ni)
#pragma unroll
    for (int kk = 0; kk < 2; ++kk)
      bfg[ni][kk] = *(const bf16x8_t*)&attnb[(size_t)bh * 4608 + (ni * 16 + fr) * 72 + (kk * 4 + g) * 8];

  const ushort* vb = vbuf + (size_t)(b * SS + p * 512) * HIDD + h * 64;
  ushort* ob = attnout + (size_t)(b * SS + p * 512) * HIDD + h * 64;

#define STGV(b_, c_)                                                        \
  _Pragma("unroll") for (int i = 0; i < 2; ++i) {                           \
    int rg = w * 2 + i;                                                     \
    int row = rg * 8 + rsub;                                                \
    gload16(&vb[(size_t)((c_) * 64 + row) * HIDD + gcol], &Vs[b_][rg * 512]); \
  }

#define PCOMP(bc, c_)                                                       \
  {                                                                         \
    f32x4_t acc[4] = {};                                                    \
    _Pragma("unroll") for (int kk = 0; kk < 2; ++kk) {                      \
      int r = w * 16 + fr;                                                  \
      bf16x8_t af = *(const bf16x8_t*)&Vs[bc][r * 64 + (((kk * 4 + g) ^ (r & 7)) * 8)]; \
      _Pragma("unroll") for (int ni = 0; ni < 4; ++ni)                      \
        acc[ni] = __builtin_amdgcn_mfma_f32_16x16x32_bf16(af, bfg[ni][kk], acc[ni], 0, 0, 0); \
    }                                                                       \
    _Pragma("unroll") for (int ni = 0; ni < 4; ++ni)                        \
    _Pragma("unroll") for (int j = 0; j < 4; ++j)                           \
      ob[(size_t)((c_) * 64 + w * 16 + g * 4 + j) * HIDD + ni * 16 + fr] = f2bf(acc[ni][j]); \
  }

#define PWAIT(n_)                                                           \
  asm volatile("s_waitcnt vmcnt(" #n_ ")" ::: "memory");                    \
  __builtin_amdgcn_s_barrier();                                             \
  __builtin_amdgcn_sched_barrier(0);

  STGV(0, 0);
  STGV(1, 1);
  for (int c = 0; c < 6; ++c) {
    STGV((c + 2) % 3, c + 2);
    PWAIT(4);
    PCOMP(c % 3, c);
    __builtin_amdgcn_s_barrier();
  }
  PWAIT(2); PCOMP(0, 6); __builtin_amdgcn_s_barrier();
  PWAIT(0); PCOMP(1, 7);
#undef STGV
#undef PCOMP
#undef PWAIT
}

extern "C" void kernel_launch(void* const* d_in, const int* in_sizes, int n_in,
                              void* d_out, int out_size, void* d_ws, size_t ws_size,
                              hipStream_t stream) {
  const float* x = (const float*)d_in[0];
  const float* Wqkv = (const float*)d_in[1];
  const float* bqkv = (const float*)d_in[2];
  const float* Wz = (const float*)d_in[3];
  const float* bz = (const float*)d_in[4];
  const float* temperature = (const float*)d_in[5];

  char* ws = (char*)d_ws;
  ushort* xb    = (ushort*)(ws + 0);           // 33,554,432 (alias: attnout)
  ushort* wqb   = (ushort*)(ws + 33554432);    // 6,291,456
  ushort* wzb   = (ushort*)(ws + 39845888);    // 2,097,152
  ushort* vbuf  = (ushort*)(ws + 41943040);    // 33,554,432
  ushort* qkvT  = (ushort*)(ws + 75497472);    // 67,108,864  [t][b][h][d][s]
  ushort* attnout = xb;  // x is dead after QKV GEMM

  // scratch inside d_out (64 MB, fully overwritten by GEMM2 at the end):
  float* dsc = (float*)d_out;
  float* Wp8 = dsc;                        // 2,097,152 floats (8 MB)
  float* sq8 = dsc + 2097152;              // 32,768 floats
  float* sk8 = dsc + 2097152 + 32768;      // 32,768 floats
  ushort* attnb = (ushort*)(dsc + 2097152 + 65536);  // 294,912 ushorts

  // 1) converts
  k_f2bf<<<dim3(16384), dim3(256), 0, stream>>>(x, xb, (MM * HIDD) / 4);
  k_f2bf<<<dim3(3072), dim3(256), 0, stream>>>(Wqkv, wqb, (NQKV * HIDD) / 4);
  k_f2bf<<<dim3(1024), dim3(256), 0, stream>>>(Wz, wzb, (HIDD * HIDD) / 4);

  // 2) QKV GEMM -> QT/KT transposed + V natural
  k_gemm8p<2, NQKV, HIDD><<<dim3(MM / 256, NQKV / 256), dim3(512), 0, stream>>>(
      xb, wqb, bqkv, nullptr, qkvT, vbuf);

  // 3) gram eighths (+fused sumsq) -> combine+softmax
  k_gram<<<dim3(64, 8), dim3(256), 0, stream>>>(qkvT, Wp8, sq8, sk8);
  k_smx<<<dim3(64), dim3(256), 0, stream>>>(Wp8, sq8, sk8, temperature, attnb);

  // 4) PV (MFMA)
  k_pv<<<dim3(64, 8), dim3(256), 0, stream>>>(vbuf, attnb, attnout);

  // 5) output GEMM -> d_out fp32 (overwrites the scratch)
  k_gemm8p<1, HIDD, HIDD><<<dim3(MM / 256, HIDD / 256), dim3(512), 0, stream>>>(
      attnout, wzb, bz, d_out, nullptr, nullptr);
}

// Round 10
// 237.012 us; speedup vs baseline: 1.0438x; 1.0438x over previous
//
#include <hip/hip_runtime.h>

#define DEVINL __device__ __forceinline__

// Problem constants
#define BB 4
#define SS 4096
#define HIDD 1024
#define HH 16
#define DH 64
#define NQKV 3072
#define MM (BB * SS)  // 16384

typedef __attribute__((ext_vector_type(8))) short bf16x8_t;
typedef __attribute__((ext_vector_type(4))) float f32x4_t;

typedef __attribute__((address_space(1))) const void GV;
typedef __attribute__((address_space(3))) void LV;

DEVINL void gload16(const void* g, void* l) {
  // async global->LDS, 16B/lane; LDS dest = wave-uniform base + lane*16
  __builtin_amdgcn_global_load_lds((GV*)g, (LV*)l, 16, 0, 0);
}

DEVINL float bf2f(ushort u) {
  union { unsigned int i; float f; } v;
  v.i = ((unsigned int)u) << 16;
  return v.f;
}
DEVINL ushort f2bf(float f) {
  unsigned int u = __float_as_uint(f);
  u = (u + 0x7fffu + ((u >> 16) & 1u)) >> 16;
  return (ushort)u;
}

// ---------------- fp32 -> bf16 convert (4 elems/thread) ----------------
__global__ __launch_bounds__(256) void k_f2bf(const float* __restrict__ src,
                                              ushort* __restrict__ dst, int n4) {
  int i = blockIdx.x * 256 + threadIdx.x;
  if (i >= n4) return;
  float4 v = ((const float4*)src)[i];
  ushort4 o;
  o.x = f2bf(v.x); o.y = f2bf(v.y); o.z = f2bf(v.z); o.w = f2bf(v.w);
  ((ushort4*)dst)[i] = o;
}

// ------- 128x128 bf16 GEMM, double-buffered, counted vmcnt, 2D XCD swizzle ---
// 4 waves (2Mx2N), per-wave 64x64 = 4x4 frags of 16x16x32. LDS 64KB -> 2
// blocks/CU. Per K-tile: stage next tile (8 gload16), vmcnt(8) (leave next
// tile's 8 in flight), barrier, compute (16 ds_read + 32 MFMA/wave), barrier.
// 2D super-tile swizzle: XCD k gets contiguous logical blocks; logical order
// groups 64 blocks into 8Mx8N super-tiles => per-XCD resident working set
// = A 2MB + B 2MB = 4MB = one L2. Swizzle: chunk ^= row&7 both sides.
// MODE 1: fp32 natural C (+bias). MODE 2: QKV split epilogue (qT/vbuf).
template <int MODE, int SNT, int NDIM, int KDIM>
__global__ __launch_bounds__(256) void k_gemm128(
    const ushort* __restrict__ A, const ushort* __restrict__ B,
    const float* __restrict__ bias, void* __restrict__ Cv,
    ushort* __restrict__ qT, ushort* __restrict__ vbuf) {
  __shared__ ushort As[2][128 * 64];
  __shared__ ushort Bs[2][128 * 64];
  constexpr int NT = KDIM >> 6;
  const int t = threadIdx.x;
  const int lane = t & 63, w = t >> 6;
  const int wm = w >> 1, wn = w & 1;
  const int fr = lane & 15, g = lane >> 4;

  // 2D super-tile XCD remap (bijective; nwg % 8 == 0)
  int wg = blockIdx.x + blockIdx.y * gridDim.x;
  int nwg = gridDim.x * gridDim.y;
  int per = nwg >> 3;
  int wgl = (wg >> 3) + (wg & 7) * per;
  int st = wgl >> 6, r0 = wgl & 63;
  int sm = st / SNT, sn = st - sm * SNT;
  const int m0 = (sm * 8 + (r0 >> 3)) * 128;
  const int n0 = (sn * 8 + (r0 & 7)) * 128;

  // staging lane constants: call covers 32 rows; row = t>>3, chunk (t&7)^(row&7)
  const int srow = t >> 3;                        // 0..31
  const int schunk = ((t & 7) ^ (srow & 7)) * 8;  // pre-swizzled 16B chunk

  f32x4_t acc[4][4] = {};

#define STAGE(slot, ktile)                                                   \
  {                                                                          \
    const int k0_ = (ktile) * 64;                                            \
    _Pragma("unroll") for (int c = 0; c < 4; ++c)                            \
        gload16(&A[(size_t)(m0 + c * 32 + srow) * KDIM + k0_ + schunk],      \
                &As[slot][(c * 32 + w * 8) * 64]);                           \
    _Pragma("unroll") for (int c = 0; c < 4; ++c)                            \
        gload16(&B[(size_t)(n0 + c * 32 + srow) * KDIM + k0_ + schunk],      \
                &Bs[slot][(c * 32 + w * 8) * 64]);                           \
  }

#define COMPUTE(slot)                                                        \
  _Pragma("unroll") for (int kk = 0; kk < 2; ++kk) {                         \
    bf16x8_t af[4], bfg[4];                                                  \
    _Pragma("unroll") for (int mi = 0; mi < 4; ++mi) {                       \
      int r = wm * 64 + mi * 16 + fr;                                        \
      af[mi] = *(const bf16x8_t*)&As[slot][r * 64 + (((kk * 4 + g) ^ (r & 7)) * 8)]; \
    }                                                                        \
    _Pragma("unroll") for (int ni = 0; ni < 4; ++ni) {                       \
      int r = wn * 64 + ni * 16 + fr;                                        \
      bfg[ni] = *(const bf16x8_t*)&Bs[slot][r * 64 + (((kk * 4 + g) ^ (r & 7)) * 8)]; \
    }                                                                        \
    _Pragma("unroll") for (int mi = 0; mi < 4; ++mi)                         \
        _Pragma("unroll") for (int ni = 0; ni < 4; ++ni)                     \
            acc[mi][ni] = __builtin_amdgcn_mfma_f32_16x16x32_bf16(           \
                af[mi], bfg[ni], acc[mi][ni], 0, 0, 0);                      \
  }

  STAGE(0, 0);
  for (int kt = 0; kt < NT; ++kt) {
    if (kt + 1 < NT) {
      STAGE((kt + 1) & 1, kt + 1);
      asm volatile("s_waitcnt vmcnt(8)" ::: "memory");
    } else {
      asm volatile("s_waitcnt vmcnt(0)" ::: "memory");
    }
    __builtin_amdgcn_s_barrier();
    __builtin_amdgcn_sched_barrier(0);
    __builtin_amdgcn_s_setprio(1);
    COMPUTE(kt & 1);
    __builtin_amdgcn_s_setprio(0);
    __builtin_amdgcn_s_barrier();
  }
#undef STAGE
#undef COMPUTE

  // epilogue: D col = lane&15, row = (lane>>4)*4 + reg (HW-verified mapping)
#pragma unroll
  for (int ni = 0; ni < 4; ++ni) {
    int col = n0 + wn * 64 + ni * 16 + fr;
    float bv = bias[col];
#pragma unroll
    for (int mi = 0; mi < 4; ++mi) {
      int rowbase = m0 + wm * 64 + mi * 16 + g * 4;
      if (MODE == 1) {
#pragma unroll
        for (int j = 0; j < 4; ++j)
          ((float*)Cv)[(size_t)(rowbase + j) * NDIM + col] = acc[mi][ni][j] + bv;
      } else {
        ushort4 o;
        o.x = f2bf(acc[mi][ni][0] + bv);
        o.y = f2bf(acc[mi][ni][1] + bv);
        o.z = f2bf(acc[mi][ni][2] + bv);
        o.w = f2bf(acc[mi][ni][3] + bv);
        if (col < 2048) {
          int tt = col >> 10;           // 0=Q, 1=K
          int hh = (col >> 6) & 15;
          int d = col & 63;
          int b = rowbase >> 12;
          int s = rowbase & 4095;
          size_t off = ((((size_t)tt * BB + b) * HH + hh) * 64 + d) * SS + s;
          *(ushort4*)&qT[off] = o;     // 4 consecutive s
        } else {
          int c = col - 2048;
          vbuf[(size_t)(rowbase + 0) * HIDD + c] = o.x;
          vbuf[(size_t)(rowbase + 1) * HIDD + c] = o.y;
          vbuf[(size_t)(rowbase + 2) * HIDD + c] = o.z;
          vbuf[(size_t)(rowbase + 3) * HIDD + c] = o.w;
        }
      }
    }
  }
}

// ------- gram eighth + fused sumsq partials -------
// grid (64 bh, 8 p): 512 s per block. 3-buffer counted-vmcnt staging.
// Partials to d_out scratch: Wp8[bh*8+p][64][64] f32, sq8/sk8[bh*8+p][64].
__global__ __launch_bounds__(256) void k_gram(const ushort* __restrict__ qT,
                                              float* __restrict__ Wp8,
                                              float* __restrict__ sq8,
                                              float* __restrict__ sk8) {
  __shared__ ushort Qs[3][64 * 64];
  __shared__ ushort Ks[3][64 * 64];
  const int bh = blockIdx.x, p = blockIdx.y;
  const ushort* Qp = qT + (size_t)bh * 64 * SS + p * 512;
  const ushort* Kp = qT + (size_t)(BB * HH + bh) * 64 * SS + p * 512;
  const int t = threadIdx.x;
  const int lane = t & 63, w = t >> 6;
  const int fr = lane & 15, g = lane >> 4;
  const int rsub = lane >> 3;
  const int gcol = ((lane & 7) ^ rsub) * 8;

  f32x4_t acc[4] = {};
  float sqa = 0.f, ska = 0.f;

#define STGG(b_, sc_)                                                       \
  _Pragma("unroll") for (int i = 0; i < 2; ++i) {                           \
    int rg = w * 2 + i;                                                     \
    int row = rg * 8 + rsub;                                                \
    gload16(&Qp[(size_t)row * SS + (sc_) * 64 + gcol], &Qs[b_][rg * 512]);  \
    gload16(&Kp[(size_t)row * SS + (sc_) * 64 + gcol], &Ks[b_][rg * 512]);  \
  }

#define GCOMP(bc)                                                           \
  {                                                                         \
    bf16x8_t af[2], bq[4][2];                                               \
    _Pragma("unroll") for (int kk = 0; kk < 2; ++kk) {                      \
      int r = w * 16 + fr;                                                  \
      af[kk] = *(const bf16x8_t*)&Qs[bc][r * 64 + (((kk * 4 + g) ^ (r & 7)) * 8)]; \
    }                                                                       \
    _Pragma("unroll") for (int ni = 0; ni < 4; ++ni)                        \
    _Pragma("unroll") for (int kk = 0; kk < 2; ++kk) {                      \
      int r2 = ni * 16 + fr;                                                \
      bq[ni][kk] = *(const bf16x8_t*)&Ks[bc][r2 * 64 + (((kk * 4 + g) ^ (r2 & 7)) * 8)]; \
    }                                                                       \
    _Pragma("unroll") for (int kk = 0; kk < 2; ++kk)                        \
    _Pragma("unroll") for (int ni = 0; ni < 4; ++ni)                        \
      acc[ni] = __builtin_amdgcn_mfma_f32_16x16x32_bf16(af[kk], bq[ni][kk], acc[ni], 0, 0, 0); \
    _Pragma("unroll") for (int kk = 0; kk < 2; ++kk)                        \
    _Pragma("unroll") for (int e = 0; e < 8; ++e) {                         \
      float fq = bf2f((ushort)af[kk][e]);                                   \
      sqa += fq * fq;                                                       \
    }                                                                       \
    _Pragma("unroll") for (int ni = 0; ni < 4; ++ni)                        \
      if (ni == w)                                                          \
        _Pragma("unroll") for (int kk = 0; kk < 2; ++kk)                    \
        _Pragma("unroll") for (int e = 0; e < 8; ++e) {                     \
          float fk = bf2f((ushort)bq[ni][kk][e]);                           \
          ska += fk * fk;                                                   \
        }                                                                   \
  }

#define GWAIT(n_)                                                           \
  asm volatile("s_waitcnt vmcnt(" #n_ ")" ::: "memory");                    \
  __builtin_amdgcn_s_barrier();                                             \
  __builtin_amdgcn_sched_barrier(0);

  STGG(0, 0);
  STGG(1, 1);
  for (int sc = 0; sc < 6; ++sc) {
    STGG((sc + 2) % 3, sc + 2);
    GWAIT(8);
    GCOMP(sc % 3);
    __builtin_amdgcn_s_barrier();
  }
  GWAIT(4); GCOMP(0); __builtin_amdgcn_s_barrier();  // sc=6 -> buf 0
  GWAIT(0); GCOMP(1);                                 // sc=7 -> buf 1
#undef STGG
#undef GCOMP
#undef GWAIT

  // reduce per-row sumsq over the 4 g-lanes; write partials
  sqa += __shfl_xor(sqa, 16, 64); sqa += __shfl_xor(sqa, 32, 64);
  ska += __shfl_xor(ska, 16, 64); ska += __shfl_xor(ska, 32, 64);
  const int bp = bh * 8 + p;
  if (g == 0) {
    sq8[bp * 64 + w * 16 + fr] = sqa;
    sk8[bp * 64 + w * 16 + fr] = ska;
  }
  float* wp = Wp8 + (size_t)bp * 4096;
#pragma unroll
  for (int ni = 0; ni < 4; ++ni)
#pragma unroll
    for (int j = 0; j < 4; ++j)
      wp[(w * 16 + g * 4 + j) * 64 + ni * 16 + fr] = acc[ni][j];
}

// ------- smx: combine partials, scale, softmax -> bf16 attnb[bh][64][72] ----
__global__ __launch_bounds__(256) void k_smx(const float* __restrict__ Wp8,
                                             const float* __restrict__ sq8,
                                             const float* __restrict__ sk8,
                                             const float* __restrict__ temperature,
                                             ushort* __restrict__ attnb) {
  __shared__ float attnf[64][65];
  __shared__ float iqL[64], ikL[64], invs[64];
  const int bh = blockIdx.x, h = bh & 15;
  const int t = threadIdx.x;
  if (t < 64) {
    float sq = 0.f, sk = 0.f;
#pragma unroll
    for (int p = 0; p < 8; ++p) {
      sq += sq8[(bh * 8 + p) * 64 + t];
      sk += sk8[(bh * 8 + p) * 64 + t];
    }
    iqL[t] = 1.0f / fmaxf(sqrtf(sq), 1e-12f);
    ikL[t] = 1.0f / fmaxf(sqrtf(sk), 1e-12f);
  }
  __syncthreads();
  float tscale = temperature[h] * (1.0f / 32.0f);
  for (int idx = t; idx < 4096; idx += 256) {
    int d = idx >> 6, e = idx & 63;
    float s = 0.f;
#pragma unroll
    for (int p = 0; p < 8; ++p) s += Wp8[(size_t)(bh * 8 + p) * 4096 + idx];
    attnf[d][e] = s * iqL[d] * ikL[e] * tscale;
  }
  __syncthreads();
  if (t < 64) {
    float m = -1e30f;
#pragma unroll 8
    for (int e = 0; e < 64; ++e) m = fmaxf(m, attnf[t][e]);
    float sum = 0.f;
#pragma unroll 8
    for (int e = 0; e < 64; ++e) {
      float v = __expf(attnf[t][e] - m);
      attnf[t][e] = v;
      sum += v;
    }
    invs[t] = 1.0f / sum;
  }
  __syncthreads();
  for (int idx = t; idx < 4096; idx += 256) {
    int d = idx >> 6, e = idx & 63;
    attnb[(size_t)bh * 4608 + d * 72 + e] = f2bf(attnf[d][e] * invs[d]);
  }
}

// ---------------- PV (MFMA): out[s][d] = sum_e V[s,e] * attn[d,e] ----------
// grid (64 bh, 8 p): 512 s-rows per block, 3-buffer counted-vmcnt staging.
__global__ __launch_bounds__(256) void k_pv(const ushort* __restrict__ vbuf,
                                            const ushort* __restrict__ attnb,
                                            ushort* __restrict__ attnout) {
  __shared__ ushort Vs[3][64 * 64];
  const int bh = blockIdx.x, p = blockIdx.y;
  const int b = bh >> 4, h = bh & 15;
  const int t = threadIdx.x;
  const int lane = t & 63, w = t >> 6;
  const int fr = lane & 15, g = lane >> 4;
  const int rsub = lane >> 3;
  const int gcol = ((lane & 7) ^ rsub) * 8;

  // B-frags straight from global attnb (L2-hot)
  bf16x8_t bfg[4][2];
#pragma unroll
  for (int ni = 0; ni < 4; ++ni)
#pragma unroll
    for (int kk = 0; kk < 2; ++kk)
      bfg[ni][kk] = *(const bf16x8_t*)&attnb[(size_t)bh * 4608 + (ni * 16 + fr) * 72 + (kk * 4 + g) * 8];

  const ushort* vb = vbuf + (size_t)(b * SS + p * 512) * HIDD + h * 64;
  ushort* ob = attnout + (size_t)(b * SS + p * 512) * HIDD + h * 64;

#define STGV(b_, c_)                                                        \
  _Pragma("unroll") for (int i = 0; i < 2; ++i) {                           \
    int rg = w * 2 + i;                                                     \
    int row = rg * 8 + rsub;                                                \
    gload16(&vb[(size_t)((c_) * 64 + row) * HIDD + gcol], &Vs[b_][rg * 512]); \
  }

#define PCOMP(bc, c_)                                                       \
  {                                                                         \
    f32x4_t acc[4] = {};                                                    \
    _Pragma("unroll") for (int kk = 0; kk < 2; ++kk) {                      \
      int r = w * 16 + fr;                                                  \
      bf16x8_t af = *(const bf16x8_t*)&Vs[bc][r * 64 + (((kk * 4 + g) ^ (r & 7)) * 8)]; \
      _Pragma("unroll") for (int ni = 0; ni < 4; ++ni)                      \
        acc[ni] = __builtin_amdgcn_mfma_f32_16x16x32_bf16(af, bfg[ni][kk], acc[ni], 0, 0, 0); \
    }                                                                       \
    _Pragma("unroll") for (int ni = 0; ni < 4; ++ni)                        \
    _Pragma("unroll") for (int j = 0; j < 4; ++j)                           \
      ob[(size_t)((c_) * 64 + w * 16 + g * 4 + j) * HIDD + ni * 16 + fr] = f2bf(acc[ni][j]); \
  }

#define PWAIT(n_)                                                           \
  asm volatile("s_waitcnt vmcnt(" #n_ ")" ::: "memory");                    \
  __builtin_amdgcn_s_barrier();                                             \
  __builtin_amdgcn_sched_barrier(0);

  STGV(0, 0);
  STGV(1, 1);
  for (int c = 0; c < 6; ++c) {
    STGV((c + 2) % 3, c + 2);
    PWAIT(4);
    PCOMP(c % 3, c);
    __builtin_amdgcn_s_barrier();
  }
  PWAIT(2); PCOMP(0, 6); __builtin_amdgcn_s_barrier();
  PWAIT(0); PCOMP(1, 7);
#undef STGV
#undef PCOMP
#undef PWAIT
}

extern "C" void kernel_launch(void* const* d_in, const int* in_sizes, int n_in,
                              void* d_out, int out_size, void* d_ws, size_t ws_size,
                              hipStream_t stream) {
  const float* x = (const float*)d_in[0];
  const float* Wqkv = (const float*)d_in[1];
  const float* bqkv = (const float*)d_in[2];
  const float* Wz = (const float*)d_in[3];
  const float* bz = (const float*)d_in[4];
  const float* temperature = (const float*)d_in[5];

  char* ws = (char*)d_ws;
  ushort* xb    = (ushort*)(ws + 0);           // 33,554,432 (alias: attnout)
  ushort* wqb   = (ushort*)(ws + 33554432);    // 6,291,456
  ushort* wzb   = (ushort*)(ws + 39845888);    // 2,097,152
  ushort* vbuf  = (ushort*)(ws + 41943040);    // 33,554,432
  ushort* qkvT  = (ushort*)(ws + 75497472);    // 67,108,864  [t][b][h][d][s]
  ushort* attnout = xb;  // x is dead after QKV GEMM

  // scratch inside d_out (64 MB, fully overwritten by GEMM2 at the end):
  float* dsc = (float*)d_out;
  float* Wp8 = dsc;                        // 2,097,152 floats (8 MB)
  float* sq8 = dsc + 2097152;              // 32,768 floats
  float* sk8 = dsc + 2097152 + 32768;      // 32,768 floats
  ushort* attnb = (ushort*)(dsc + 2097152 + 65536);  // 294,912 ushorts

  // 1) converts
  k_f2bf<<<dim3(16384), dim3(256), 0, stream>>>(x, xb, (MM * HIDD) / 4);
  k_f2bf<<<dim3(3072), dim3(256), 0, stream>>>(Wqkv, wqb, (NQKV * HIDD) / 4);
  k_f2bf<<<dim3(1024), dim3(256), 0, stream>>>(Wz, wzb, (HIDD * HIDD) / 4);

  // 2) QKV GEMM -> QT/KT transposed + V natural (grid 128 Mtiles x 24 Ntiles)
  k_gemm128<2, 3, NQKV, HIDD><<<dim3(128, 24), dim3(256), 0, stream>>>(
      xb, wqb, bqkv, nullptr, qkvT, vbuf);

  // 3) gram eighths (+fused sumsq) -> combine+softmax
  k_gram<<<dim3(64, 8), dim3(256), 0, stream>>>(qkvT, Wp8, sq8, sk8);
  k_smx<<<dim3(64), dim3(256), 0, stream>>>(Wp8, sq8, sk8, temperature, attnb);

  // 4) PV (MFMA)
  k_pv<<<dim3(64, 8), dim3(256), 0, stream>>>(vbuf, attnb, attnout);

  // 5) output GEMM -> d_out fp32 (grid 128 x 8; overwrites the scratch)
  k_gemm128<1, 1, HIDD, HIDD><<<dim3(128, 8), dim3(256), 0, stream>>>(
      attnout, wzb, bz, d_out, nullptr, nullptr);
}

// Round 11
// 224.140 us; speedup vs baseline: 1.1037x; 1.0574x over previous
//
#include <hip/hip_runtime.h>

#define DEVINL __device__ __forceinline__

// Problem constants
#define BB 4
#define SS 4096
#define HIDD 1024
#define HH 16
#define DH 64
#define NQKV 3072
#define MM (BB * SS)  // 16384

typedef __attribute__((ext_vector_type(8))) short bf16x8_t;
typedef __attribute__((ext_vector_type(4))) float f32x4_t;

typedef __attribute__((address_space(1))) const void GV;
typedef __attribute__((address_space(3))) void LV;

DEVINL void gload16(const void* g, void* l) {
  // async global->LDS, 16B/lane; LDS dest = wave-uniform base + lane*16
  __builtin_amdgcn_global_load_lds((GV*)g, (LV*)l, 16, 0, 0);
}

DEVINL float bf2f(ushort u) {
  union { unsigned int i; float f; } v;
  v.i = ((unsigned int)u) << 16;
  return v.f;
}
DEVINL ushort f2bf(float f) {
  unsigned int u = __float_as_uint(f);
  u = (u + 0x7fffu + ((u >> 16) & 1u)) >> 16;
  return (ushort)u;
}

// ---------------- fp32 -> bf16 convert (4 elems/thread) ----------------
__global__ __launch_bounds__(256) void k_f2bf(const float* __restrict__ src,
                                              ushort* __restrict__ dst, int n4) {
  int i = blockIdx.x * 256 + threadIdx.x;
  if (i >= n4) return;
  float4 v = ((const float4*)src)[i];
  ushort4 o;
  o.x = f2bf(v.x); o.y = f2bf(v.y); o.z = f2bf(v.z); o.w = f2bf(v.w);
  ((ushort4*)dst)[i] = o;
}

// ---------------- 8-phase 256x256 bf16 GEMM, compile-time geometry ----------
// 8 waves (2M x 4N), BK=64, acc 8x4 frags of 16x16x32. 2 LDS K-tile slots per
// operand + dummy; per phase {ds_read quad (+B at q0) | stage 1 half-tile},
// barrier/setprio around MFMA, counted vmcnt(4) at ph3/ph7 only. J fully
// unrolled (KDIM constexpr) so all addresses are base+constant.
template <int MODE, int MDIM, int NDIM, int KDIM>
__global__ __launch_bounds__(512, 2) void k_gemm8p(
    const ushort* __restrict__ A, const ushort* __restrict__ B,
    const float* __restrict__ bias, void* __restrict__ Cv,
    ushort* __restrict__ qT, ushort* __restrict__ vbuf) {
  __shared__ ushort As0[256 * 64];
  __shared__ ushort As1[256 * 64];
  __shared__ ushort Bs0[256 * 64];
  __shared__ ushort Bs1[256 * 64];
  __shared__ ushort Dmy[4096];
  constexpr int NT = KDIM >> 6;
  const int t = threadIdx.x;
  const int m0 = blockIdx.x * 256, n0 = blockIdx.y * 256;
  const int lane = t & 63, wid = t >> 6;
  const int wm = wid >> 2, wn = wid & 3;   // 2M x 4N waves
  const int fr = lane & 15, g = lane >> 4;
  const int srow = t >> 3;                        // 0..63 (row within 64-row call)
  const int schunk = ((t & 7) ^ (srow & 7)) * 8;  // pre-swizzled 16B chunk
  // per-thread staging bases (all further addressing is +constexpr)
  const ushort* Ab = A + (size_t)(m0 + srow) * KDIM + schunk;
  const ushort* Bb = B + (size_t)(n0 + srow) * KDIM + schunk;

  f32x4_t acc[8][4] = {};
  bf16x8_t af[2][2], bfr[4][2];

#define STG(ls_, gb_, tile, hf)                                             \
  {                                                                         \
    if ((tile) < NT) {                                                      \
      gload16((gb_) + (size_t)((hf) * 128) * KDIM + (tile) * 64,            \
              (ls_) + ((hf) * 128 + wid * 8) * 64);                         \
      gload16((gb_) + (size_t)((hf) * 128 + 64) * KDIM + (tile) * 64,       \
              (ls_) + ((hf) * 128 + wid * 8 + 64) * 64);                    \
    } else {                                                                \
      gload16((gb_), Dmy + wid * 512);                                      \
      gload16((gb_), Dmy + wid * 512);                                      \
    }                                                                       \
  }

#define LDA(as_, q)                                                         \
  _Pragma("unroll") for (int ii = 0; ii < 2; ++ii)                          \
  _Pragma("unroll") for (int kk = 0; kk < 2; ++kk) {                        \
    int r = wm * 128 + ((q) * 2 + ii) * 16 + fr;                            \
    af[ii][kk] = *(const bf16x8_t*)&(as_)[r * 64 + (((kk * 4 + g) ^ (r & 7)) * 8)]; \
  }

#define LDB(bs_)                                                            \
  _Pragma("unroll") for (int ni = 0; ni < 4; ++ni)                          \
  _Pragma("unroll") for (int kk = 0; kk < 2; ++kk) {                        \
    int r = wn * 64 + ni * 16 + fr;                                         \
    bfr[ni][kk] = *(const bf16x8_t*)&(bs_)[r * 64 + (((kk * 4 + g) ^ (r & 7)) * 8)]; \
  }

#define MMA(q)                                                              \
  _Pragma("unroll") for (int kk = 0; kk < 2; ++kk)                          \
  _Pragma("unroll") for (int ii = 0; ii < 2; ++ii)                          \
  _Pragma("unroll") for (int ni = 0; ni < 4; ++ni)                          \
    acc[(q) * 2 + ii][ni] = __builtin_amdgcn_mfma_f32_16x16x32_bf16(        \
        af[ii][kk], bfr[ni][kk], acc[(q) * 2 + ii][ni], 0, 0, 0);

#define BAR1                                                                \
  __builtin_amdgcn_s_barrier();                                             \
  __builtin_amdgcn_s_setprio(1);

#define BAR2                                                                \
  __builtin_amdgcn_s_setprio(0);                                            \
  __builtin_amdgcn_s_barrier();

#define BAR2VM                                                              \
  __builtin_amdgcn_s_setprio(0);                                            \
  asm volatile("s_waitcnt vmcnt(4)" ::: "memory");                          \
  __builtin_amdgcn_s_barrier();                                             \
  __builtin_amdgcn_sched_barrier(0);

  // prologue: B(0), A(0), B(1) fully staged; loop ph0/ph1 stage A(1).
  STG(Bs0, Bb, 0, 0); STG(Bs0, Bb, 0, 1);
  STG(As0, Ab, 0, 0); STG(As0, Ab, 0, 1);
  STG(Bs1, Bb, 1, 0); STG(Bs1, Bb, 1, 1);
  asm volatile("s_waitcnt vmcnt(4)" ::: "memory");
  __builtin_amdgcn_s_barrier();
  __builtin_amdgcn_sched_barrier(0);

#pragma unroll
  for (int J = 0; J < (NT >> 1); ++J) {
    const int T0 = 2 * J, T1 = 2 * J + 1;
    LDA(As0, 0); LDB(Bs0); STG(As1, Ab, T1, 0);
    BAR1; MMA(0); BAR2;
    LDA(As0, 1); STG(As1, Ab, T1, 1);
    BAR1; MMA(1); BAR2;
    LDA(As0, 2); STG(Bs0, Bb, T0 + 2, 0);
    BAR1; MMA(2); BAR2;
    LDA(As0, 3); STG(Bs0, Bb, T0 + 2, 1);
    BAR1; MMA(3); BAR2VM;
    LDA(As1, 0); LDB(Bs1); STG(As0, Ab, T0 + 2, 0);
    BAR1; MMA(0); BAR2;
    LDA(As1, 1); STG(As0, Ab, T0 + 2, 1);
    BAR1; MMA(1); BAR2;
    LDA(As1, 2); STG(Bs1, Bb, T1 + 2, 0);
    BAR1; MMA(2); BAR2;
    LDA(As1, 3); STG(Bs1, Bb, T1 + 2, 1);
    BAR1; MMA(3); BAR2VM;
  }
#undef STG
#undef LDA
#undef LDB
#undef MMA
#undef BAR1
#undef BAR2
#undef BAR2VM

  // epilogue: D col = lane&15, row = (lane>>4)*4 + reg (HW-verified mapping)
#pragma unroll
  for (int ni = 0; ni < 4; ++ni) {
    int col = n0 + wn * 64 + ni * 16 + fr;
    float bv = bias[col];
#pragma unroll
    for (int mi = 0; mi < 8; ++mi) {
      int rowbase = m0 + wm * 128 + mi * 16 + g * 4;
      if (MODE == 1) {
#pragma unroll
        for (int j = 0; j < 4; ++j)
          ((float*)Cv)[(size_t)(rowbase + j) * NDIM + col] = acc[mi][ni][j] + bv;
      } else {
        ushort4 o;
        o.x = f2bf(acc[mi][ni][0] + bv);
        o.y = f2bf(acc[mi][ni][1] + bv);
        o.z = f2bf(acc[mi][ni][2] + bv);
        o.w = f2bf(acc[mi][ni][3] + bv);
        if (col < 2048) {
          int tt = col >> 10;           // 0=Q, 1=K
          int hh = (col >> 6) & 15;
          int d = col & 63;
          int b = rowbase >> 12;
          int s = rowbase & 4095;
          size_t off = ((((size_t)tt * BB + b) * HH + hh) * 64 + d) * SS + s;
          *(ushort4*)&qT[off] = o;     // 4 consecutive s
        } else {
          int c = col - 2048;
          vbuf[(size_t)(rowbase + 0) * HIDD + c] = o.x;
          vbuf[(size_t)(rowbase + 1) * HIDD + c] = o.y;
          vbuf[(size_t)(rowbase + 2) * HIDD + c] = o.z;
          vbuf[(size_t)(rowbase + 3) * HIDD + c] = o.w;
        }
      }
    }
  }
}

// ------- gram eighth + fused sumsq partials -------
// grid (64 bh, 8 p): 512 s per block. 3-buffer counted-vmcnt staging.
// NO runtime-indexed register arrays (rule #20): K-row sumsq uses static ni
// with wave-uniform (ni == w) predicate.
// Partials to d_out scratch: Wp8[bh*8+p][64][64] f32, sq8/sk8[bh*8+p][64].
__global__ __launch_bounds__(256) void k_gram(const ushort* __restrict__ qT,
                                              float* __restrict__ Wp8,
                                              float* __restrict__ sq8,
                                              float* __restrict__ sk8) {
  __shared__ ushort Qs[3][64 * 64];
  __shared__ ushort Ks[3][64 * 64];
  const int bh = blockIdx.x, p = blockIdx.y;
  const ushort* Qp = qT + (size_t)bh * 64 * SS + p * 512;
  const ushort* Kp = qT + (size_t)(BB * HH + bh) * 64 * SS + p * 512;
  const int t = threadIdx.x;
  const int lane = t & 63, w = t >> 6;
  const int fr = lane & 15, g = lane >> 4;
  const int rsub = lane >> 3;
  const int gcol = ((lane & 7) ^ rsub) * 8;

  f32x4_t acc[4] = {};
  float sqa = 0.f, ska = 0.f;

#define STGG(b_, sc_)                                                       \
  _Pragma("unroll") for (int i = 0; i < 2; ++i) {                           \
    int rg = w * 2 + i;                                                     \
    int row = rg * 8 + rsub;                                                \
    gload16(&Qp[(size_t)row * SS + (sc_) * 64 + gcol], &Qs[b_][rg * 512]);  \
    gload16(&Kp[(size_t)row * SS + (sc_) * 64 + gcol], &Ks[b_][rg * 512]);  \
  }

#define GCOMP(bc)                                                           \
  {                                                                         \
    bf16x8_t af[2], bq[4][2];                                               \
    _Pragma("unroll") for (int kk = 0; kk < 2; ++kk) {                      \
      int r = w * 16 + fr;                                                  \
      af[kk] = *(const bf16x8_t*)&Qs[bc][r * 64 + (((kk * 4 + g) ^ (r & 7)) * 8)]; \
    }                                                                       \
    _Pragma("unroll") for (int ni = 0; ni < 4; ++ni)                        \
    _Pragma("unroll") for (int kk = 0; kk < 2; ++kk) {                      \
      int r2 = ni * 16 + fr;                                                \
      bq[ni][kk] = *(const bf16x8_t*)&Ks[bc][r2 * 64 + (((kk * 4 + g) ^ (r2 & 7)) * 8)]; \
    }                                                                       \
    _Pragma("unroll") for (int kk = 0; kk < 2; ++kk)                        \
    _Pragma("unroll") for (int ni = 0; ni < 4; ++ni)                        \
      acc[ni] = __builtin_amdgcn_mfma_f32_16x16x32_bf16(af[kk], bq[ni][kk], acc[ni], 0, 0, 0); \
    _Pragma("unroll") for (int kk = 0; kk < 2; ++kk)                        \
    _Pragma("unroll") for (int e = 0; e < 8; ++e) {                         \
      float fq = bf2f((ushort)af[kk][e]);                                   \
      sqa += fq * fq;                                                       \
    }                                                                       \
    _Pragma("unroll") for (int ni = 0; ni < 4; ++ni)                        \
      if (ni == w)                                                          \
        _Pragma("unroll") for (int kk = 0; kk < 2; ++kk)                    \
        _Pragma("unroll") for (int e = 0; e < 8; ++e) {                     \
          float fk = bf2f((ushort)bq[ni][kk][e]);                           \
          ska += fk * fk;                                                   \
        }                                                                   \
  }

#define GWAIT(n_)                                                           \
  asm volatile("s_waitcnt vmcnt(" #n_ ")" ::: "memory");                    \
  __builtin_amdgcn_s_barrier();                                             \
  __builtin_amdgcn_sched_barrier(0);

  STGG(0, 0);
  STGG(1, 1);
  for (int sc = 0; sc < 6; ++sc) {
    STGG((sc + 2) % 3, sc + 2);
    GWAIT(8);
    GCOMP(sc % 3);
    __builtin_amdgcn_s_barrier();
  }
  GWAIT(4); GCOMP(0); __builtin_amdgcn_s_barrier();  // sc=6 -> buf 0
  GWAIT(0); GCOMP(1);                                 // sc=7 -> buf 1
#undef STGG
#undef GCOMP
#undef GWAIT

  // reduce per-row sumsq over the 4 g-lanes; write partials
  sqa += __shfl_xor(sqa, 16, 64); sqa += __shfl_xor(sqa, 32, 64);
  ska += __shfl_xor(ska, 16, 64); ska += __shfl_xor(ska, 32, 64);
  const int bp = bh * 8 + p;
  if (g == 0) {
    sq8[bp * 64 + w * 16 + fr] = sqa;
    sk8[bp * 64 + w * 16 + fr] = ska;
  }
  float* wp = Wp8 + (size_t)bp * 4096;
#pragma unroll
  for (int ni = 0; ni < 4; ++ni)
#pragma unroll
    for (int j = 0; j < 4; ++j)
      wp[(w * 16 + g * 4 + j) * 64 + ni * 16 + fr] = acc[ni][j];
}

// ------- smx: combine partials, scale, softmax -> bf16 attnb[bh][64][72] ----
__global__ __launch_bounds__(256) void k_smx(const float* __restrict__ Wp8,
                                             const float* __restrict__ sq8,
                                             const float* __restrict__ sk8,
                                             const float* __restrict__ temperature,
                                             ushort* __restrict__ attnb) {
  __shared__ float attnf[64][65];
  __shared__ float iqL[64], ikL[64], invs[64];
  const int bh = blockIdx.x, h = bh & 15;
  const int t = threadIdx.x;
  if (t < 64) {
    float sq = 0.f, sk = 0.f;
#pragma unroll
    for (int p = 0; p < 8; ++p) {
      sq += sq8[(bh * 8 + p) * 64 + t];
      sk += sk8[(bh * 8 + p) * 64 + t];
    }
    iqL[t] = 1.0f / fmaxf(sqrtf(sq), 1e-12f);
    ikL[t] = 1.0f / fmaxf(sqrtf(sk), 1e-12f);
  }
  __syncthreads();
  float tscale = temperature[h] * (1.0f / 32.0f);
  for (int idx = t; idx < 4096; idx += 256) {
    int d = idx >> 6, e = idx & 63;
    float s = 0.f;
#pragma unroll
    for (int p = 0; p < 8; ++p) s += Wp8[(size_t)(bh * 8 + p) * 4096 + idx];
    attnf[d][e] = s * iqL[d] * ikL[e] * tscale;
  }
  __syncthreads();
  if (t < 64) {
    float m = -1e30f;
#pragma unroll 8
    for (int e = 0; e < 64; ++e) m = fmaxf(m, attnf[t][e]);
    float sum = 0.f;
#pragma unroll 8
    for (int e = 0; e < 64; ++e) {
      float v = __expf(attnf[t][e] - m);
      attnf[t][e] = v;
      sum += v;
    }
    invs[t] = 1.0f / sum;
  }
  __syncthreads();
  for (int idx = t; idx < 4096; idx += 256) {
    int d = idx >> 6, e = idx & 63;
    attnb[(size_t)bh * 4608 + d * 72 + e] = f2bf(attnf[d][e] * invs[d]);
  }
}

// ---------------- PV (MFMA): out[s][d] = sum_e V[s,e] * attn[d,e] ----------
// grid (64 bh, 8 p): 512 s-rows per block, 3-buffer counted-vmcnt staging.
__global__ __launch_bounds__(256) void k_pv(const ushort* __restrict__ vbuf,
                                            const ushort* __restrict__ attnb,
                                            ushort* __restrict__ attnout) {
  __shared__ ushort Vs[3][64 * 64];
  const int bh = blockIdx.x, p = blockIdx.y;
  const int b = bh >> 4, h = bh & 15;
  const int t = threadIdx.x;
  const int lane = t & 63, w = t >> 6;
  const int fr = lane & 15, g = lane >> 4;
  const int rsub = lane >> 3;
  const int gcol = ((lane & 7) ^ rsub) * 8;

  // B-frags straight from global attnb (L2-hot)
  bf16x8_t bfg[4][2];
#pragma unroll
  for (int ni = 0; ni < 4; ++ni)
#pragma unroll
    for (int kk = 0; kk < 2; ++kk)
      bfg[ni][kk] = *(const bf16x8_t*)&attnb[(size_t)bh * 4608 + (ni * 16 + fr) * 72 + (kk * 4 + g) * 8];

  const ushort* vb = vbuf + (size_t)(b * SS + p * 512) * HIDD + h * 64;
  ushort* ob = attnout + (size_t)(b * SS + p * 512) * HIDD + h * 64;

#define STGV(b_, c_)                                                        \
  _Pragma("unroll") for (int i = 0; i < 2; ++i) {                           \
    int rg = w * 2 + i;                                                     \
    int row = rg * 8 + rsub;                                                \
    gload16(&vb[(size_t)((c_) * 64 + row) * HIDD + gcol], &Vs[b_][rg * 512]); \
  }

#define PCOMP(bc, c_)                                                       \
  {                                                                         \
    f32x4_t acc[4] = {};                                                    \
    _Pragma("unroll") for (int kk = 0; kk < 2; ++kk) {                      \
      int r = w * 16 + fr;                                                  \
      bf16x8_t af = *(const bf16x8_t*)&Vs[bc][r * 64 + (((kk * 4 + g) ^ (r & 7)) * 8)]; \
      _Pragma("unroll") for (int ni = 0; ni < 4; ++ni)                      \
        acc[ni] = __builtin_amdgcn_mfma_f32_16x16x32_bf16(af, bfg[ni][kk], acc[ni], 0, 0, 0); \
    }                                                                       \
    _Pragma("unroll") for (int ni = 0; ni < 4; ++ni)                        \
    _Pragma("unroll") for (int j = 0; j < 4; ++j)                           \
      ob[(size_t)((c_) * 64 + w * 16 + g * 4 + j) * HIDD + ni * 16 + fr] = f2bf(acc[ni][j]); \
  }

#define PWAIT(n_)                                                           \
  asm volatile("s_waitcnt vmcnt(" #n_ ")" ::: "memory");                    \
  __builtin_amdgcn_s_barrier();                                             \
  __builtin_amdgcn_sched_barrier(0);

  STGV(0, 0);
  STGV(1, 1);
  for (int c = 0; c < 6; ++c) {
    STGV((c + 2) % 3, c + 2);
    PWAIT(4);
    PCOMP(c % 3, c);
    __builtin_amdgcn_s_barrier();
  }
  PWAIT(2); PCOMP(0, 6); __builtin_amdgcn_s_barrier();
  PWAIT(0); PCOMP(1, 7);
#undef STGV
#undef PCOMP
#undef PWAIT
}

extern "C" void kernel_launch(void* const* d_in, const int* in_sizes, int n_in,
                              void* d_out, int out_size, void* d_ws, size_t ws_size,
                              hipStream_t stream) {
  const float* x = (const float*)d_in[0];
  const float* Wqkv = (const float*)d_in[1];
  const float* bqkv = (const float*)d_in[2];
  const float* Wz = (const float*)d_in[3];
  const float* bz = (const float*)d_in[4];
  const float* temperature = (const float*)d_in[5];

  char* ws = (char*)d_ws;
  ushort* xb    = (ushort*)(ws + 0);           // 33,554,432 (alias: attnout)
  ushort* wqb   = (ushort*)(ws + 33554432);    // 6,291,456
  ushort* wzb   = (ushort*)(ws + 39845888);    // 2,097,152
  ushort* vbuf  = (ushort*)(ws + 41943040);    // 33,554,432
  ushort* qkvT  = (ushort*)(ws + 75497472);    // 67,108,864  [t][b][h][d][s]
  ushort* attnout = xb;  // x is dead after QKV GEMM

  // scratch inside d_out (64 MB, fully overwritten by GEMM2 at the end):
  float* dsc = (float*)d_out;
  float* Wp8 = dsc;                        // 2,097,152 floats (8 MB)
  float* sq8 = dsc + 2097152;              // 32,768 floats
  float* sk8 = dsc + 2097152 + 32768;      // 32,768 floats
  ushort* attnb = (ushort*)(dsc + 2097152 + 65536);  // 294,912 ushorts

  // 1) converts
  k_f2bf<<<dim3(16384), dim3(256), 0, stream>>>(x, xb, (MM * HIDD) / 4);
  k_f2bf<<<dim3(3072), dim3(256), 0, stream>>>(Wqkv, wqb, (NQKV * HIDD) / 4);
  k_f2bf<<<dim3(1024), dim3(256), 0, stream>>>(Wz, wzb, (HIDD * HIDD) / 4);

  // 2) QKV GEMM -> QT/KT transposed + V natural
  k_gemm8p<2, MM, NQKV, HIDD><<<dim3(MM / 256, NQKV / 256), dim3(512), 0, stream>>>(
      xb, wqb, bqkv, nullptr, qkvT, vbuf);

  // 3) gram eighths (+fused sumsq) -> combine+softmax
  k_gram<<<dim3(64, 8), dim3(256), 0, stream>>>(qkvT, Wp8, sq8, sk8);
  k_smx<<<dim3(64), dim3(256), 0, stream>>>(Wp8, sq8, sk8, temperature, attnb);

  // 4) PV (MFMA)
  k_pv<<<dim3(64, 8), dim3(256), 0, stream>>>(vbuf, attnb, attnout);

  // 5) output GEMM -> d_out fp32 (overwrites the scratch)
  k_gemm8p<1, MM, HIDD, HIDD><<<dim3(MM / 256, HIDD / 256), dim3(512), 0, stream>>>(
      attnout, wzb, bz, d_out, nullptr, nullptr);
}

// Round 12
// 215.467 us; speedup vs baseline: 1.1482x; 1.0402x over previous
//
#include <hip/hip_runtime.h>

#define DEVINL __device__ __forceinline__

// Problem constants
#define BB 4
#define SS 4096
#define HIDD 1024
#define HH 16
#define DH 64
#define NQKV 3072
#define MM (BB * SS)  // 16384

typedef __attribute__((ext_vector_type(8))) short bf16x8_t;
typedef __attribute__((ext_vector_type(4))) float f32x4_t;

typedef __attribute__((address_space(1))) const void GV;
typedef __attribute__((address_space(3))) void LV;

DEVINL void gload16(const void* g, void* l) {
  // async global->LDS, 16B/lane; LDS dest = wave-uniform base + lane*16
  __builtin_amdgcn_global_load_lds((GV*)g, (LV*)l, 16, 0, 0);
}

DEVINL float bf2f(ushort u) {
  union { unsigned int i; float f; } v;
  v.i = ((unsigned int)u) << 16;
  return v.f;
}
DEVINL ushort f2bf(float f) {
  unsigned int u = __float_as_uint(f);
  u = (u + 0x7fffu + ((u >> 16) & 1u)) >> 16;
  return (ushort)u;
}

// ---------------- fp32 -> bf16 convert (4 elems/thread) ----------------
__global__ __launch_bounds__(256) void k_f2bf(const float* __restrict__ src,
                                              ushort* __restrict__ dst, int n4) {
  int i = blockIdx.x * 256 + threadIdx.x;
  if (i >= n4) return;
  float4 v = ((const float4*)src)[i];
  ushort4 o;
  o.x = f2bf(v.x); o.y = f2bf(v.y); o.z = f2bf(v.z); o.w = f2bf(v.w);
  ((ushort4*)dst)[i] = o;
}

// ---------------- 8-phase 256x256 bf16 GEMM, compile-time geometry ----------
// 8 waves (2M x 4N), BK=64, acc 8x4 frags of 16x16x32. 2 LDS K-tile slots per
// operand + dummy; per phase {ds_read quad (+B at q0) | stage 1 half-tile},
// barrier/setprio around MFMA, counted vmcnt(4) at ph3/ph7 only.
// MODE 2 Q/K epilogue: per-wave LDS-transposed stores -> 128B bursts along s
// (fix for partial-sector 8B scattered writes; WRITE_SIZE 144->~103 MB).
template <int MODE, int MDIM, int NDIM, int KDIM>
__global__ __launch_bounds__(512, 2) void k_gemm8p(
    const ushort* __restrict__ A, const ushort* __restrict__ B,
    const float* __restrict__ bias, void* __restrict__ Cv,
    ushort* __restrict__ qT, ushort* __restrict__ vbuf) {
  __shared__ ushort As0[256 * 64];
  __shared__ ushort As1[256 * 64];
  __shared__ ushort Bs0[256 * 64];
  __shared__ ushort Bs1[256 * 64];
  __shared__ ushort Dmy[4096];
  constexpr int NT = KDIM >> 6;
  const int t = threadIdx.x;
  const int m0 = blockIdx.x * 256, n0 = blockIdx.y * 256;
  const int lane = t & 63, wid = t >> 6;
  const int wm = wid >> 2, wn = wid & 3;   // 2M x 4N waves
  const int fr = lane & 15, g = lane >> 4;
  const int srow = t >> 3;                        // 0..63 (row within 64-row call)
  const int schunk = ((t & 7) ^ (srow & 7)) * 8;  // pre-swizzled 16B chunk
  // per-thread staging bases (all further addressing is +constexpr)
  const ushort* Ab = A + (size_t)(m0 + srow) * KDIM + schunk;
  const ushort* Bb = B + (size_t)(n0 + srow) * KDIM + schunk;

  f32x4_t acc[8][4] = {};
  bf16x8_t af[2][2], bfr[4][2];

#define STG(ls_, gb_, tile, hf)                                             \
  {                                                                         \
    if ((tile) < NT) {                                                      \
      gload16((gb_) + (size_t)((hf) * 128) * KDIM + (tile) * 64,            \
              (ls_) + ((hf) * 128 + wid * 8) * 64);                         \
      gload16((gb_) + (size_t)((hf) * 128 + 64) * KDIM + (tile) * 64,       \
              (ls_) + ((hf) * 128 + wid * 8 + 64) * 64);                    \
    } else {                                                                \
      gload16((gb_), Dmy + wid * 512);                                      \
      gload16((gb_), Dmy + wid * 512);                                      \
    }                                                                       \
  }

#define LDA(as_, q)                                                         \
  _Pragma("unroll") for (int ii = 0; ii < 2; ++ii)                          \
  _Pragma("unroll") for (int kk = 0; kk < 2; ++kk) {                        \
    int r = wm * 128 + ((q) * 2 + ii) * 16 + fr;                            \
    af[ii][kk] = *(const bf16x8_t*)&(as_)[r * 64 + (((kk * 4 + g) ^ (r & 7)) * 8)]; \
  }

#define LDB(bs_)                                                            \
  _Pragma("unroll") for (int ni = 0; ni < 4; ++ni)                          \
  _Pragma("unroll") for (int kk = 0; kk < 2; ++kk) {                        \
    int r = wn * 64 + ni * 16 + fr;                                         \
    bfr[ni][kk] = *(const bf16x8_t*)&(bs_)[r * 64 + (((kk * 4 + g) ^ (r & 7)) * 8)]; \
  }

#define MMA(q)                                                              \
  _Pragma("unroll") for (int kk = 0; kk < 2; ++kk)                          \
  _Pragma("unroll") for (int ii = 0; ii < 2; ++ii)                          \
  _Pragma("unroll") for (int ni = 0; ni < 4; ++ni)                          \
    acc[(q) * 2 + ii][ni] = __builtin_amdgcn_mfma_f32_16x16x32_bf16(        \
        af[ii][kk], bfr[ni][kk], acc[(q) * 2 + ii][ni], 0, 0, 0);

#define BAR1                                                                \
  __builtin_amdgcn_s_barrier();                                             \
  __builtin_amdgcn_s_setprio(1);

#define BAR2                                                                \
  __builtin_amdgcn_s_setprio(0);                                            \
  __builtin_amdgcn_s_barrier();

#define BAR2VM                                                              \
  __builtin_amdgcn_s_setprio(0);                                            \
  asm volatile("s_waitcnt vmcnt(4)" ::: "memory");                          \
  __builtin_amdgcn_s_barrier();                                             \
  __builtin_amdgcn_sched_barrier(0);

  // prologue: B(0), A(0), B(1) fully staged; loop ph0/ph1 stage A(1).
  STG(Bs0, Bb, 0, 0); STG(Bs0, Bb, 0, 1);
  STG(As0, Ab, 0, 0); STG(As0, Ab, 0, 1);
  STG(Bs1, Bb, 1, 0); STG(Bs1, Bb, 1, 1);
  asm volatile("s_waitcnt vmcnt(4)" ::: "memory");
  __builtin_amdgcn_s_barrier();
  __builtin_amdgcn_sched_barrier(0);

#pragma unroll
  for (int J = 0; J < (NT >> 1); ++J) {
    const int T0 = 2 * J, T1 = 2 * J + 1;
    LDA(As0, 0); LDB(Bs0); STG(As1, Ab, T1, 0);
    BAR1; MMA(0); BAR2;
    LDA(As0, 1); STG(As1, Ab, T1, 1);
    BAR1; MMA(1); BAR2;
    LDA(As0, 2); STG(Bs0, Bb, T0 + 2, 0);
    BAR1; MMA(2); BAR2;
    LDA(As0, 3); STG(Bs0, Bb, T0 + 2, 1);
    BAR1; MMA(3); BAR2VM;
    LDA(As1, 0); LDB(Bs1); STG(As0, Ab, T0 + 2, 0);
    BAR1; MMA(0); BAR2;
    LDA(As1, 1); STG(As0, Ab, T0 + 2, 1);
    BAR1; MMA(1); BAR2;
    LDA(As1, 2); STG(Bs1, Bb, T1 + 2, 0);
    BAR1; MMA(2); BAR2;
    LDA(As1, 3); STG(Bs1, Bb, T1 + 2, 1);
    BAR1; MMA(3); BAR2VM;
  }
#undef STG
#undef LDA
#undef LDB
#undef MMA
#undef BAR1
#undef BAR2
#undef BAR2VM

  // ---- epilogue ----
  // reclaim LDS: all compute done; pending tail gloads target Dmy only.
  __syncthreads();

  if (MODE == 1) {
    // D col = lane&15, row = (lane>>4)*4 + reg (HW-verified mapping)
#pragma unroll
    for (int ni = 0; ni < 4; ++ni) {
      int col = n0 + wn * 64 + ni * 16 + fr;
      float bv = bias[col];
#pragma unroll
      for (int mi = 0; mi < 8; ++mi) {
        int rowbase = m0 + wm * 128 + mi * 16 + g * 4;
#pragma unroll
        for (int j = 0; j < 4; ++j)
          ((float*)Cv)[(size_t)(rowbase + j) * NDIM + col] = acc[mi][ni][j] + bv;
      }
    }
  } else {
    const int colbase = n0 + wn * 64;  // wave-uniform 64-col block
    if (colbase < 2048) {
      // Q/K: per-wave LDS transpose -> qT[tt][b][hh][d][s], 16B/lane along s.
      // wave scratch: 64 d-rows x stride 72 ushorts (16B-aligned rows).
      ushort* scr = (wid < 2 ? As0 : wid < 4 ? As1 : wid < 6 ? Bs0 : Bs1) +
                    (wid & 1) * 8192;
      const int tt = colbase >> 10;
      const int hh = (colbase >> 6) & 15;
      const int bb = m0 >> 12;
      const int sbase0 = (m0 & 4095) + wm * 128;
      const int ch = lane & 7, dq = lane >> 3;
      ushort* qbase = qT + (((size_t)tt * BB + bb) * HH + hh) * 64 * SS;
#pragma unroll
      for (int half = 0; half < 2; ++half) {
        // store acc -> scr[d = ni*16+fr][sl = mi_*16+g*4+j], pair-packed
#pragma unroll
        for (int ni = 0; ni < 4; ++ni) {
          float bv = bias[colbase + ni * 16 + fr];
#pragma unroll
          for (int mi_ = 0; mi_ < 4; ++mi_) {
#pragma unroll
            for (int jp = 0; jp < 2; ++jp) {
              unsigned int lo = f2bf(acc[half * 4 + mi_][ni][jp * 2] + bv);
              unsigned int hi = f2bf(acc[half * 4 + mi_][ni][jp * 2 + 1] + bv);
              *(unsigned int*)&scr[(ni * 16 + fr) * 72 + mi_ * 16 + g * 4 + jp * 2] =
                  lo | (hi << 16);
            }
          }
        }
        asm volatile("s_waitcnt lgkmcnt(0)" ::: "memory");
        // readback rows of 64 s-values, store 16B/lane contiguous in s
#pragma unroll
        for (int dr = 0; dr < 8; ++dr) {
          int d = dr * 8 + dq;
          int4 v = *(const int4*)&scr[d * 72 + ch * 8];
          *(int4*)&qbase[(size_t)d * SS + sbase0 + half * 64 + ch * 8] = v;
        }
        asm volatile("s_waitcnt lgkmcnt(0)" ::: "memory");
      }
    } else {
      // V: natural layout (32B bursts along c) — unchanged
#pragma unroll
      for (int ni = 0; ni < 4; ++ni) {
        int col = colbase + ni * 16 + fr;
        float bv = bias[col];
        int c = col - 2048;
#pragma unroll
        for (int mi = 0; mi < 8; ++mi) {
          int rowbase = m0 + wm * 128 + mi * 16 + g * 4;
          vbuf[(size_t)(rowbase + 0) * HIDD + c] = f2bf(acc[mi][ni][0] + bv);
          vbuf[(size_t)(rowbase + 1) * HIDD + c] = f2bf(acc[mi][ni][1] + bv);
          vbuf[(size_t)(rowbase + 2) * HIDD + c] = f2bf(acc[mi][ni][2] + bv);
          vbuf[(size_t)(rowbase + 3) * HIDD + c] = f2bf(acc[mi][ni][3] + bv);
        }
      }
    }
  }
}

// ------- gram eighth + fused sumsq partials -------
// grid (64 bh, 8 p): 512 s per block. 3-buffer counted-vmcnt staging.
// NO runtime-indexed register arrays (rule #20): K-row sumsq uses static ni
// with wave-uniform (ni == w) predicate.
// Partials to d_out scratch: Wp8[bh*8+p][64][64] f32, sq8/sk8[bh*8+p][64].
__global__ __launch_bounds__(256) void k_gram(const ushort* __restrict__ qT,
                                              float* __restrict__ Wp8,
                                              float* __restrict__ sq8,
                                              float* __restrict__ sk8) {
  __shared__ ushort Qs[3][64 * 64];
  __shared__ ushort Ks[3][64 * 64];
  const int bh = blockIdx.x, p = blockIdx.y;
  const ushort* Qp = qT + (size_t)bh * 64 * SS + p * 512;
  const ushort* Kp = qT + (size_t)(BB * HH + bh) * 64 * SS + p * 512;
  const int t = threadIdx.x;
  const int lane = t & 63, w = t >> 6;
  const int fr = lane & 15, g = lane >> 4;
  const int rsub = lane >> 3;
  const int gcol = ((lane & 7) ^ rsub) * 8;

  f32x4_t acc[4] = {};
  float sqa = 0.f, ska = 0.f;

#define STGG(b_, sc_)                                                       \
  _Pragma("unroll") for (int i = 0; i < 2; ++i) {                           \
    int rg = w * 2 + i;                                                     \
    int row = rg * 8 + rsub;                                                \
    gload16(&Qp[(size_t)row * SS + (sc_) * 64 + gcol], &Qs[b_][rg * 512]);  \
    gload16(&Kp[(size_t)row * SS + (sc_) * 64 + gcol], &Ks[b_][rg * 512]);  \
  }

#define GCOMP(bc)                                                           \
  {                                                                         \
    bf16x8_t af[2], bq[4][2];                                               \
    _Pragma("unroll") for (int kk = 0; kk < 2; ++kk) {                      \
      int r = w * 16 + fr;                                                  \
      af[kk] = *(const bf16x8_t*)&Qs[bc][r * 64 + (((kk * 4 + g) ^ (r & 7)) * 8)]; \
    }                                                                       \
    _Pragma("unroll") for (int ni = 0; ni < 4; ++ni)                        \
    _Pragma("unroll") for (int kk = 0; kk < 2; ++kk) {                      \
      int r2 = ni * 16 + fr;                                                \
      bq[ni][kk] = *(const bf16x8_t*)&Ks[bc][r2 * 64 + (((kk * 4 + g) ^ (r2 & 7)) * 8)]; \
    }                                                                       \
    _Pragma("unroll") for (int kk = 0; kk < 2; ++kk)                        \
    _Pragma("unroll") for (int ni = 0; ni < 4; ++ni)                        \
      acc[ni] = __builtin_amdgcn_mfma_f32_16x16x32_bf16(af[kk], bq[ni][kk], acc[ni], 0, 0, 0); \
    _Pragma("unroll") for (int kk = 0; kk < 2; ++kk)                        \
    _Pragma("unroll") for (int e = 0; e < 8; ++e) {                         \
      float fq = bf2f((ushort)af[kk][e]);                                   \
      sqa += fq * fq;                                                       \
    }                                                                       \
    _Pragma("unroll") for (int ni = 0; ni < 4; ++ni)                        \
      if (ni == w)                                                          \
        _Pragma("unroll") for (int kk = 0; kk < 2; ++kk)                    \
        _Pragma("unroll") for (int e = 0; e < 8; ++e) {                     \
          float fk = bf2f((ushort)bq[ni][kk][e]);                           \
          ska += fk * fk;                                                   \
        }                                                                   \
  }

#define GWAIT(n_)                                                           \
  asm volatile("s_waitcnt vmcnt(" #n_ ")" ::: "memory");                    \
  __builtin_amdgcn_s_barrier();                                             \
  __builtin_amdgcn_sched_barrier(0);

  STGG(0, 0);
  STGG(1, 1);
  for (int sc = 0; sc < 6; ++sc) {
    STGG((sc + 2) % 3, sc + 2);
    GWAIT(8);
    GCOMP(sc % 3);
    __builtin_amdgcn_s_barrier();
  }
  GWAIT(4); GCOMP(0); __builtin_amdgcn_s_barrier();  // sc=6 -> buf 0
  GWAIT(0); GCOMP(1);                                 // sc=7 -> buf 1
#undef STGG
#undef GCOMP
#undef GWAIT

  // reduce per-row sumsq over the 4 g-lanes; write partials
  sqa += __shfl_xor(sqa, 16, 64); sqa += __shfl_xor(sqa, 32, 64);
  ska += __shfl_xor(ska, 16, 64); ska += __shfl_xor(ska, 32, 64);
  const int bp = bh * 8 + p;
  if (g == 0) {
    sq8[bp * 64 + w * 16 + fr] = sqa;
    sk8[bp * 64 + w * 16 + fr] = ska;
  }
  float* wp = Wp8 + (size_t)bp * 4096;
#pragma unroll
  for (int ni = 0; ni < 4; ++ni)
#pragma unroll
    for (int j = 0; j < 4; ++j)
      wp[(w * 16 + g * 4 + j) * 64 + ni * 16 + fr] = acc[ni][j];
}

// ------- smx: combine partials, scale, softmax -> bf16 attnb[bh][64][72] ----
__global__ __launch_bounds__(256) void k_smx(const float* __restrict__ Wp8,
                                             const float* __restrict__ sq8,
                                             const float* __restrict__ sk8,
                                             const float* __restrict__ temperature,
                                             ushort* __restrict__ attnb) {
  __shared__ float attnf[64][65];
  __shared__ float iqL[64], ikL[64], invs[64];
  const int bh = blockIdx.x, h = bh & 15;
  const int t = threadIdx.x;
  if (t < 64) {
    float sq = 0.f, sk = 0.f;
#pragma unroll
    for (int p = 0; p < 8; ++p) {
      sq += sq8[(bh * 8 + p) * 64 + t];
      sk += sk8[(bh * 8 + p) * 64 + t];
    }
    iqL[t] = 1.0f / fmaxf(sqrtf(sq), 1e-12f);
    ikL[t] = 1.0f / fmaxf(sqrtf(sk), 1e-12f);
  }
  __syncthreads();
  float tscale = temperature[h] * (1.0f / 32.0f);
  for (int idx = t; idx < 4096; idx += 256) {
    int d = idx >> 6, e = idx & 63;
    float s = 0.f;
#pragma unroll
    for (int p = 0; p < 8; ++p) s += Wp8[(size_t)(bh * 8 + p) * 4096 + idx];
    attnf[d][e] = s * iqL[d] * ikL[e] * tscale;
  }
  __syncthreads();
  if (t < 64) {
    float m = -1e30f;
#pragma unroll 8
    for (int e = 0; e < 64; ++e) m = fmaxf(m, attnf[t][e]);
    float sum = 0.f;
#pragma unroll 8
    for (int e = 0; e < 64; ++e) {
      float v = __expf(attnf[t][e] - m);
      attnf[t][e] = v;
      sum += v;
    }
    invs[t] = 1.0f / sum;
  }
  __syncthreads();
  for (int idx = t; idx < 4096; idx += 256) {
    int d = idx >> 6, e = idx & 63;
    attnb[(size_t)bh * 4608 + d * 72 + e] = f2bf(attnf[d][e] * invs[d]);
  }
}

// ---------------- PV (MFMA): out[s][d] = sum_e V[s,e] * attn[d,e] ----------
// grid (64 bh, 8 p): 512 s-rows per block, 3-buffer counted-vmcnt staging.
__global__ __launch_bounds__(256) void k_pv(const ushort* __restrict__ vbuf,
                                            const ushort* __restrict__ attnb,
                                            ushort* __restrict__ attnout) {
  __shared__ ushort Vs[3][64 * 64];
  const int bh = blockIdx.x, p = blockIdx.y;
  const int b = bh >> 4, h = bh & 15;
  const int t = threadIdx.x;
  const int lane = t & 63, w = t >> 6;
  const int fr = lane & 15, g = lane >> 4;
  const int rsub = lane >> 3;
  const int gcol = ((lane & 7) ^ rsub) * 8;

  // B-frags straight from global attnb (L2-hot)
  bf16x8_t bfg[4][2];
#pragma unroll
  for (int ni = 0; ni < 4; ++ni)
#pragma unroll
    for (int kk = 0; kk < 2; ++kk)
      bfg[ni][kk] = *(const bf16x8_t*)&attnb[(size_t)bh * 4608 + (ni * 16 + fr) * 72 + (kk * 4 + g) * 8];

  const ushort* vb = vbuf + (size_t)(b * SS + p * 512) * HIDD + h * 64;
  ushort* ob = attnout + (size_t)(b * SS + p * 512) * HIDD + h * 64;

#define STGV(b_, c_)                                                        \
  _Pragma("unroll") for (int i = 0; i < 2; ++i) {                           \
    int rg = w * 2 + i;                                                     \
    int row = rg * 8 + rsub;                                                \
    gload16(&vb[(size_t)((c_) * 64 + row) * HIDD + gcol], &Vs[b_][rg * 512]); \
  }

#define PCOMP(bc, c_)                                                       \
  {                                                                         \
    f32x4_t acc[4] = {};                                                    \
    _Pragma("unroll") for (int kk = 0; kk < 2; ++kk) {                      \
      int r = w * 16 + fr;                                                  \
      bf16x8_t af = *(const bf16x8_t*)&Vs[bc][r * 64 + (((kk * 4 + g) ^ (r & 7)) * 8)]; \
      _Pragma("unroll") for (int ni = 0; ni < 4; ++ni)                      \
        acc[ni] = __builtin_amdgcn_mfma_f32_16x16x32_bf16(af, bfg[ni][kk], acc[ni], 0, 0, 0); \
    }                                                                       \
    _Pragma("unroll") for (int ni = 0; ni < 4; ++ni)                        \
    _Pragma("unroll") for (int j = 0; j < 4; ++j)                           \
      ob[(size_t)((c_) * 64 + w * 16 + g * 4 + j) * HIDD + ni * 16 + fr] = f2bf(acc[ni][j]); \
  }

#define PWAIT(n_)                                                           \
  asm volatile("s_waitcnt vmcnt(" #n_ ")" ::: "memory");                    \
  __builtin_amdgcn_s_barrier();                                             \
  __builtin_amdgcn_sched_barrier(0);

  STGV(0, 0);
  STGV(1, 1);
  for (int c = 0; c < 6; ++c) {
    STGV((c + 2) % 3, c + 2);
    PWAIT(4);
    PCOMP(c % 3, c);
    __builtin_amdgcn_s_barrier();
  }
  PWAIT(2); PCOMP(0, 6); __builtin_amdgcn_s_barrier();
  PWAIT(0); PCOMP(1, 7);
#undef STGV
#undef PCOMP
#undef PWAIT
}

extern "C" void kernel_launch(void* const* d_in, const int* in_sizes, int n_in,
                              void* d_out, int out_size, void* d_ws, size_t ws_size,
                              hipStream_t stream) {
  const float* x = (const float*)d_in[0];
  const float* Wqkv = (const float*)d_in[1];
  const float* bqkv = (const float*)d_in[2];
  const float* Wz = (const float*)d_in[3];
  const float* bz = (const float*)d_in[4];
  const float* temperature = (const float*)d_in[5];

  char* ws = (char*)d_ws;
  ushort* xb    = (ushort*)(ws + 0);           // 33,554,432 (alias: attnout)
  ushort* wqb   = (ushort*)(ws + 33554432);    // 6,291,456
  ushort* wzb   = (ushort*)(ws + 39845888);    // 2,097,152
  ushort* vbuf  = (ushort*)(ws + 41943040);    // 33,554,432
  ushort* qkvT  = (ushort*)(ws + 75497472);    // 67,108,864  [t][b][h][d][s]
  ushort* attnout = xb;  // x is dead after QKV GEMM

  // scratch inside d_out (64 MB, fully overwritten by GEMM2 at the end):
  float* dsc = (float*)d_out;
  float* Wp8 = dsc;                        // 2,097,152 floats (8 MB)
  float* sq8 = dsc + 2097152;              // 32,768 floats
  float* sk8 = dsc + 2097152 + 32768;      // 32,768 floats
  ushort* attnb = (ushort*)(dsc + 2097152 + 65536);  // 294,912 ushorts

  // 1) converts
  k_f2bf<<<dim3(16384), dim3(256), 0, stream>>>(x, xb, (MM * HIDD) / 4);
  k_f2bf<<<dim3(3072), dim3(256), 0, stream>>>(Wqkv, wqb, (NQKV * HIDD) / 4);
  k_f2bf<<<dim3(1024), dim3(256), 0, stream>>>(Wz, wzb, (HIDD * HIDD) / 4);

  // 2) QKV GEMM -> QT/KT transposed + V natural
  k_gemm8p<2, MM, NQKV, HIDD><<<dim3(MM / 256, NQKV / 256), dim3(512), 0, stream>>>(
      xb, wqb, bqkv, nullptr, qkvT, vbuf);

  // 3) gram eighths (+fused sumsq) -> combine+softmax
  k_gram<<<dim3(64, 8), dim3(256), 0, stream>>>(qkvT, Wp8, sq8, sk8);
  k_smx<<<dim3(64), dim3(256), 0, stream>>>(Wp8, sq8, sk8, temperature, attnb);

  // 4) PV (MFMA)
  k_pv<<<dim3(64, 8), dim3(256), 0, stream>>>(vbuf, attnb, attnout);

  // 5) output GEMM -> d_out fp32 (overwrites the scratch)
  k_gemm8p<1, MM, HIDD, HIDD><<<dim3(MM / 256, HIDD / 256), dim3(512), 0, stream>>>(
      attnout, wzb, bz, d_out, nullptr, nullptr);
}

// Round 13
// 209.901 us; speedup vs baseline: 1.1786x; 1.0265x over previous
//
#include <hip/hip_runtime.h>

#define DEVINL __device__ __forceinline__

// Problem constants
#define BB 4
#define SS 4096
#define HIDD 1024
#define HH 16
#define DH 64
#define NQKV 3072
#define MM (BB * SS)  // 16384

typedef __attribute__((ext_vector_type(8))) short bf16x8_t;
typedef __attribute__((ext_vector_type(4))) float f32x4_t;

typedef __attribute__((address_space(1))) const void GV;
typedef __attribute__((address_space(3))) void LV;

DEVINL void gload16(const void* g, void* l) {
  // async global->LDS, 16B/lane; LDS dest = wave-uniform base + lane*16
  __builtin_amdgcn_global_load_lds((GV*)g, (LV*)l, 16, 0, 0);
}

DEVINL float bf2f(ushort u) {
  union { unsigned int i; float f; } v;
  v.i = ((unsigned int)u) << 16;
  return v.f;
}
DEVINL ushort f2bf(float f) {
  unsigned int u = __float_as_uint(f);
  u = (u + 0x7fffu + ((u >> 16) & 1u)) >> 16;
  return (ushort)u;
}

// ------- fused fp32 -> bf16 convert for x|Wqkv|Wz (contiguous dst) -------
// dst ushort4 ranges: x [0,4194304), Wqkv [4194304,4980736), Wz [4980736,5242880)
__global__ __launch_bounds__(256) void k_f2bf3(const float* __restrict__ x,
                                               const float* __restrict__ wq,
                                               const float* __restrict__ wz,
                                               ushort* __restrict__ dst) {
  int i = blockIdx.x * 256 + threadIdx.x;
  const float* src;
  int off;
  if (i < 4194304) { src = x; off = i; }
  else if (i < 4980736) { src = wq; off = i - 4194304; }
  else { src = wz; off = i - 4980736; }
  float4 v = ((const float4*)src)[off];
  ushort4 o;
  o.x = f2bf(v.x); o.y = f2bf(v.y); o.z = f2bf(v.z); o.w = f2bf(v.w);
  ((ushort4*)dst)[i] = o;
}

// ---------------- 8-phase 256x256 bf16 GEMM, compile-time geometry ----------
// 8 waves (2M x 4N), BK=64, acc 8x4 frags of 16x16x32. 2 LDS K-tile slots per
// operand + dummy. Barrier-relaxed schedule: single barrier per phase
// {LDA;STG; bar; MFMA}, EXCEPT ph3/ph7 which keep {bar; MMA; vmcnt(4); bar}
// (As-slot overwrite at ph3->ph4 / ph7->ph0' can race in-flight q3 ds_reads
// otherwise). sched_barrier(0) after every barrier blocks cross-bar hoisting.
// MODE 2 Q/K epilogue: per-wave LDS-transposed stores -> 128B bursts along s.
template <int MODE, int MDIM, int NDIM, int KDIM>
__global__ __launch_bounds__(512, 2) void k_gemm8p(
    const ushort* __restrict__ A, const ushort* __restrict__ B,
    const float* __restrict__ bias, void* __restrict__ Cv,
    ushort* __restrict__ qT, ushort* __restrict__ vbuf) {
  __shared__ ushort As0[256 * 64];
  __shared__ ushort As1[256 * 64];
  __shared__ ushort Bs0[256 * 64];
  __shared__ ushort Bs1[256 * 64];
  __shared__ ushort Dmy[4096];
  constexpr int NT = KDIM >> 6;
  const int t = threadIdx.x;
  const int m0 = blockIdx.x * 256, n0 = blockIdx.y * 256;
  const int lane = t & 63, wid = t >> 6;
  const int wm = wid >> 2, wn = wid & 3;   // 2M x 4N waves
  const int fr = lane & 15, g = lane >> 4;
  const int srow = t >> 3;                        // 0..63 (row within 64-row call)
  const int schunk = ((t & 7) ^ (srow & 7)) * 8;  // pre-swizzled 16B chunk
  // per-thread staging bases (all further addressing is +constexpr)
  const ushort* Ab = A + (size_t)(m0 + srow) * KDIM + schunk;
  const ushort* Bb = B + (size_t)(n0 + srow) * KDIM + schunk;

  f32x4_t acc[8][4] = {};
  bf16x8_t af[2][2], bfr[4][2];

#define STG(ls_, gb_, tile, hf)                                             \
  {                                                                         \
    if ((tile) < NT) {                                                      \
      gload16((gb_) + (size_t)((hf) * 128) * KDIM + (tile) * 64,            \
              (ls_) + ((hf) * 128 + wid * 8) * 64);                         \
      gload16((gb_) + (size_t)((hf) * 128 + 64) * KDIM + (tile) * 64,       \
              (ls_) + ((hf) * 128 + wid * 8 + 64) * 64);                    \
    } else {                                                                \
      gload16((gb_), Dmy + wid * 512);                                      \
      gload16((gb_), Dmy + wid * 512);                                      \
    }                                                                       \
  }

#define LDA(as_, q)                                                         \
  _Pragma("unroll") for (int ii = 0; ii < 2; ++ii)                          \
  _Pragma("unroll") for (int kk = 0; kk < 2; ++kk) {                        \
    int r = wm * 128 + ((q) * 2 + ii) * 16 + fr;                            \
    af[ii][kk] = *(const bf16x8_t*)&(as_)[r * 64 + (((kk * 4 + g) ^ (r & 7)) * 8)]; \
  }

#define LDB(bs_)                                                            \
  _Pragma("unroll") for (int ni = 0; ni < 4; ++ni)                          \
  _Pragma("unroll") for (int kk = 0; kk < 2; ++kk) {                        \
    int r = wn * 64 + ni * 16 + fr;                                         \
    bfr[ni][kk] = *(const bf16x8_t*)&(bs_)[r * 64 + (((kk * 4 + g) ^ (r & 7)) * 8)]; \
  }

#define MMA(q)                                                              \
  _Pragma("unroll") for (int kk = 0; kk < 2; ++kk)                          \
  _Pragma("unroll") for (int ii = 0; ii < 2; ++ii)                          \
  _Pragma("unroll") for (int ni = 0; ni < 4; ++ni)                          \
    acc[(q) * 2 + ii][ni] = __builtin_amdgcn_mfma_f32_16x16x32_bf16(        \
        af[ii][kk], bfr[ni][kk], acc[(q) * 2 + ii][ni], 0, 0, 0);

#define PHBAR                                                               \
  __builtin_amdgcn_s_barrier();                                             \
  __builtin_amdgcn_sched_barrier(0);

#define MMAP(q)                                                             \
  __builtin_amdgcn_s_setprio(1);                                            \
  MMA(q);                                                                   \
  __builtin_amdgcn_s_setprio(0);

#define VMFENCE                                                             \
  asm volatile("s_waitcnt vmcnt(4)" ::: "memory");                          \
  PHBAR;

  // prologue: B(0), A(0), B(1) fully staged; loop ph0/ph1 stage A(1).
  STG(Bs0, Bb, 0, 0); STG(Bs0, Bb, 0, 1);
  STG(As0, Ab, 0, 0); STG(As0, Ab, 0, 1);
  STG(Bs1, Bb, 1, 0); STG(Bs1, Bb, 1, 1);
  VMFENCE;

#pragma unroll
  for (int J = 0; J < (NT >> 1); ++J) {
    const int T0 = 2 * J, T1 = 2 * J + 1;
    // ph0
    LDA(As0, 0); LDB(Bs0); STG(As1, Ab, T1, 0);
    PHBAR; MMAP(0);
    // ph1
    LDA(As0, 1); STG(As1, Ab, T1, 1);
    PHBAR; MMAP(1);
    // ph2
    LDA(As0, 2); STG(Bs0, Bb, T0 + 2, 0);
    PHBAR; MMAP(2);
    // ph3 (double barrier: MMA(3) must drain before As0 overwrite at ph4)
    LDA(As0, 3); STG(Bs0, Bb, T0 + 2, 1);
    PHBAR; MMAP(3);
    VMFENCE;
    // ph4
    LDA(As1, 0); LDB(Bs1); STG(As0, Ab, T0 + 2, 0);
    PHBAR; MMAP(0);
    // ph5
    LDA(As1, 1); STG(As0, Ab, T0 + 2, 1);
    PHBAR; MMAP(1);
    // ph6
    LDA(As1, 2); STG(Bs1, Bb, T1 + 2, 0);
    PHBAR; MMAP(2);
    // ph7 (double barrier)
    LDA(As1, 3); STG(Bs1, Bb, T1 + 2, 1);
    PHBAR; MMAP(3);
    VMFENCE;
  }
#undef STG
#undef LDA
#undef LDB
#undef MMA
#undef MMAP
#undef PHBAR
#undef VMFENCE

  // ---- epilogue ----
  // reclaim LDS: all compute done; pending tail gloads target Dmy only.
  __syncthreads();

  if (MODE == 1) {
    // D col = lane&15, row = (lane>>4)*4 + reg (HW-verified mapping)
#pragma unroll
    for (int ni = 0; ni < 4; ++ni) {
      int col = n0 + wn * 64 + ni * 16 + fr;
      float bv = bias[col];
#pragma unroll
      for (int mi = 0; mi < 8; ++mi) {
        int rowbase = m0 + wm * 128 + mi * 16 + g * 4;
#pragma unroll
        for (int j = 0; j < 4; ++j)
          ((float*)Cv)[(size_t)(rowbase + j) * NDIM + col] = acc[mi][ni][j] + bv;
      }
    }
  } else {
    const int colbase = n0 + wn * 64;  // wave-uniform 64-col block
    if (colbase < 2048) {
      // Q/K: per-wave LDS transpose -> qT[tt][b][hh][d][s], 16B/lane along s.
      // wave scratch: 64 d-rows x stride 72 ushorts (16B-aligned rows).
      ushort* scr = (wid < 2 ? As0 : wid < 4 ? As1 : wid < 6 ? Bs0 : Bs1) +
                    (wid & 1) * 8192;
      const int tt = colbase >> 10;
      const int hh = (colbase >> 6) & 15;
      const int bb = m0 >> 12;
      const int sbase0 = (m0 & 4095) + wm * 128;
      const int ch = lane & 7, dq = lane >> 3;
      ushort* qbase = qT + (((size_t)tt * BB + bb) * HH + hh) * 64 * SS;
#pragma unroll
      for (int half = 0; half < 2; ++half) {
        // store acc -> scr[d = ni*16+fr][sl = mi_*16+g*4+j], pair-packed
#pragma unroll
        for (int ni = 0; ni < 4; ++ni) {
          float bv = bias[colbase + ni * 16 + fr];
#pragma unroll
          for (int mi_ = 0; mi_ < 4; ++mi_) {
#pragma unroll
            for (int jp = 0; jp < 2; ++jp) {
              unsigned int lo = f2bf(acc[half * 4 + mi_][ni][jp * 2] + bv);
              unsigned int hi = f2bf(acc[half * 4 + mi_][ni][jp * 2 + 1] + bv);
              *(unsigned int*)&scr[(ni * 16 + fr) * 72 + mi_ * 16 + g * 4 + jp * 2] =
                  lo | (hi << 16);
            }
          }
        }
        asm volatile("s_waitcnt lgkmcnt(0)" ::: "memory");
        // readback rows of 64 s-values, store 16B/lane contiguous in s
#pragma unroll
        for (int dr = 0; dr < 8; ++dr) {
          int d = dr * 8 + dq;
          int4 v = *(const int4*)&scr[d * 72 + ch * 8];
          *(int4*)&qbase[(size_t)d * SS + sbase0 + half * 64 + ch * 8] = v;
        }
        asm volatile("s_waitcnt lgkmcnt(0)" ::: "memory");
      }
    } else {
      // V: natural layout (32B bursts along c) — unchanged
#pragma unroll
      for (int ni = 0; ni < 4; ++ni) {
        int col = colbase + ni * 16 + fr;
        float bv = bias[col];
        int c = col - 2048;
#pragma unroll
        for (int mi = 0; mi < 8; ++mi) {
          int rowbase = m0 + wm * 128 + mi * 16 + g * 4;
          vbuf[(size_t)(rowbase + 0) * HIDD + c] = f2bf(acc[mi][ni][0] + bv);
          vbuf[(size_t)(rowbase + 1) * HIDD + c] = f2bf(acc[mi][ni][1] + bv);
          vbuf[(size_t)(rowbase + 2) * HIDD + c] = f2bf(acc[mi][ni][2] + bv);
          vbuf[(size_t)(rowbase + 3) * HIDD + c] = f2bf(acc[mi][ni][3] + bv);
        }
      }
    }
  }
}

// ------- gram eighth + fused sumsq partials -------
// grid (64 bh, 8 p): 512 s per block. 3-buffer counted-vmcnt staging.
// NO runtime-indexed register arrays (rule #20): K-row sumsq uses static ni
// with wave-uniform (ni == w) predicate.
// Partials to d_out scratch: Wp8[bh*8+p][64][64] f32, sq8/sk8[bh*8+p][64].
__global__ __launch_bounds__(256) void k_gram(const ushort* __restrict__ qT,
                                              float* __restrict__ Wp8,
                                              float* __restrict__ sq8,
                                              float* __restrict__ sk8) {
  __shared__ ushort Qs[3][64 * 64];
  __shared__ ushort Ks[3][64 * 64];
  const int bh = blockIdx.x, p = blockIdx.y;
  const ushort* Qp = qT + (size_t)bh * 64 * SS + p * 512;
  const ushort* Kp = qT + (size_t)(BB * HH + bh) * 64 * SS + p * 512;
  const int t = threadIdx.x;
  const int lane = t & 63, w = t >> 6;
  const int fr = lane & 15, g = lane >> 4;
  const int rsub = lane >> 3;
  const int gcol = ((lane & 7) ^ rsub) * 8;

  f32x4_t acc[4] = {};
  float sqa = 0.f, ska = 0.f;

#define STGG(b_, sc_)                                                       \
  _Pragma("unroll") for (int i = 0; i < 2; ++i) {                           \
    int rg = w * 2 + i;                                                     \
    int row = rg * 8 + rsub;                                                \
    gload16(&Qp[(size_t)row * SS + (sc_) * 64 + gcol], &Qs[b_][rg * 512]);  \
    gload16(&Kp[(size_t)row * SS + (sc_) * 64 + gcol], &Ks[b_][rg * 512]);  \
  }

#define GCOMP(bc)                                                           \
  {                                                                         \
    bf16x8_t af[2], bq[4][2];                                               \
    _Pragma("unroll") for (int kk = 0; kk < 2; ++kk) {                      \
      int r = w * 16 + fr;                                                  \
      af[kk] = *(const bf16x8_t*)&Qs[bc][r * 64 + (((kk * 4 + g) ^ (r & 7)) * 8)]; \
    }                                                                       \
    _Pragma("unroll") for (int ni = 0; ni < 4; ++ni)                        \
    _Pragma("unroll") for (int kk = 0; kk < 2; ++kk) {                      \
      int r2 = ni * 16 + fr;                                                \
      bq[ni][kk] = *(const bf16x8_t*)&Ks[bc][r2 * 64 + (((kk * 4 + g) ^ (r2 & 7)) * 8)]; \
    }                                                                       \
    _Pragma("unroll") for (int kk = 0; kk < 2; ++kk)                        \
    _Pragma("unroll") for (int ni = 0; ni < 4; ++ni)                        \
      acc[ni] = __builtin_amdgcn_mfma_f32_16x16x32_bf16(af[kk], bq[ni][kk], acc[ni], 0, 0, 0); \
    _Pragma("unroll") for (int kk = 0; kk < 2; ++kk)                        \
    _Pragma("unroll") for (int e = 0; e < 8; ++e) {                         \
      float fq = bf2f((ushort)af[kk][e]);                                   \
      sqa += fq * fq;                                                       \
    }                                                                       \
    _Pragma("unroll") for (int ni = 0; ni < 4; ++ni)                        \
      if (ni == w)                                                          \
        _Pragma("unroll") for (int kk = 0; kk < 2; ++kk)                    \
        _Pragma("unroll") for (int e = 0; e < 8; ++e) {                     \
          float fk = bf2f((ushort)bq[ni][kk][e]);                           \
          ska += fk * fk;                                                   \
        }                                                                   \
  }

#define GWAIT(n_)                                                           \
  asm volatile("s_waitcnt vmcnt(" #n_ ")" ::: "memory");                    \
  __builtin_amdgcn_s_barrier();                                             \
  __builtin_amdgcn_sched_barrier(0);

  STGG(0, 0);
  STGG(1, 1);
  for (int sc = 0; sc < 6; ++sc) {
    STGG((sc + 2) % 3, sc + 2);
    GWAIT(8);
    GCOMP(sc % 3);
    __builtin_amdgcn_s_barrier();
  }
  GWAIT(4); GCOMP(0); __builtin_amdgcn_s_barrier();  // sc=6 -> buf 0
  GWAIT(0); GCOMP(1);                                 // sc=7 -> buf 1
#undef STGG
#undef GCOMP
#undef GWAIT

  // reduce per-row sumsq over the 4 g-lanes; write partials
  sqa += __shfl_xor(sqa, 16, 64); sqa += __shfl_xor(sqa, 32, 64);
  ska += __shfl_xor(ska, 16, 64); ska += __shfl_xor(ska, 32, 64);
  const int bp = bh * 8 + p;
  if (g == 0) {
    sq8[bp * 64 + w * 16 + fr] = sqa;
    sk8[bp * 64 + w * 16 + fr] = ska;
  }
  float* wp = Wp8 + (size_t)bp * 4096;
#pragma unroll
  for (int ni = 0; ni < 4; ++ni)
#pragma unroll
    for (int j = 0; j < 4; ++j)
      wp[(w * 16 + g * 4 + j) * 64 + ni * 16 + fr] = acc[ni][j];
}

// ------- smx: combine partials, scale, softmax -> bf16 attnb[bh][64][72] ----
__global__ __launch_bounds__(256) void k_smx(const float* __restrict__ Wp8,
                                             const float* __restrict__ sq8,
                                             const float* __restrict__ sk8,
                                             const float* __restrict__ temperature,
                                             ushort* __restrict__ attnb) {
  __shared__ float attnf[64][65];
  __shared__ float iqL[64], ikL[64], invs[64];
  const int bh = blockIdx.x, h = bh & 15;
  const int t = threadIdx.x;
  if (t < 64) {
    float sq = 0.f, sk = 0.f;
#pragma unroll
    for (int p = 0; p < 8; ++p) {
      sq += sq8[(bh * 8 + p) * 64 + t];
      sk += sk8[(bh * 8 + p) * 64 + t];
    }
    iqL[t] = 1.0f / fmaxf(sqrtf(sq), 1e-12f);
    ikL[t] = 1.0f / fmaxf(sqrtf(sk), 1e-12f);
  }
  __syncthreads();
  float tscale = temperature[h] * (1.0f / 32.0f);
  for (int idx = t; idx < 4096; idx += 256) {
    int d = idx >> 6, e = idx & 63;
    float s = 0.f;
#pragma unroll
    for (int p = 0; p < 8; ++p) s += Wp8[(size_t)(bh * 8 + p) * 4096 + idx];
    attnf[d][e] = s * iqL[d] * ikL[e] * tscale;
  }
  __syncthreads();
  if (t < 64) {
    float m = -1e30f;
#pragma unroll 8
    for (int e = 0; e < 64; ++e) m = fmaxf(m, attnf[t][e]);
    float sum = 0.f;
#pragma unroll 8
    for (int e = 0; e < 64; ++e) {
      float v = __expf(attnf[t][e] - m);
      attnf[t][e] = v;
      sum += v;
    }
    invs[t] = 1.0f / sum;
  }
  __syncthreads();
  for (int idx = t; idx < 4096; idx += 256) {
    int d = idx >> 6, e = idx & 63;
    attnb[(size_t)bh * 4608 + d * 72 + e] = f2bf(attnf[d][e] * invs[d]);
  }
}

// ---------------- PV (MFMA): out[s][d] = sum_e V[s,e] * attn[d,e] ----------
// grid (64 bh, 8 p): 512 s-rows per block, 3-buffer counted-vmcnt staging.
__global__ __launch_bounds__(256) void k_pv(const ushort* __restrict__ vbuf,
                                            const ushort* __restrict__ attnb,
                                            ushort* __restrict__ attnout) {
  __shared__ ushort Vs[3][64 * 64];
  const int bh = blockIdx.x, p = blockIdx.y;
  const int b = bh >> 4, h = bh & 15;
  const int t = threadIdx.x;
  const int lane = t & 63, w = t >> 6;
  const int fr = lane & 15, g = lane >> 4;
  const int rsub = lane >> 3;
  const int gcol = ((lane & 7) ^ rsub) * 8;

  // B-frags straight from global attnb (L2-hot)
  bf16x8_t bfg[4][2];
#pragma unroll
  for (int ni = 0; ni < 4; ++ni)
#pragma unroll
    for (int kk = 0; kk < 2; ++kk)
      bfg[ni][kk] = *(const bf16x8_t*)&attnb[(size_t)bh * 4608 + (ni * 16 + fr) * 72 + (kk * 4 + g) * 8];

  const ushort* vb = vbuf + (size_t)(b * SS + p * 512) * HIDD + h * 64;
  ushort* ob = attnout + (size_t)(b * SS + p * 512) * HIDD + h * 64;

#define STGV(b_, c_)                                                        \
  _Pragma("unroll") for (int i = 0; i < 2; ++i) {                           \
    int rg = w * 2 + i;                                                     \
    int row = rg * 8 + rsub;                                                \
    gload16(&vb[(size_t)((c_) * 64 + row) * HIDD + gcol], &Vs[b_][rg * 512]); \
  }

#define PCOMP(bc, c_)                                                       \
  {                                                                         \
    f32x4_t acc[4] = {};                                                    \
    _Pragma("unroll") for (int kk = 0; kk < 2; ++kk) {                      \
      int r = w * 16 + fr;                                                  \
      bf16x8_t af = *(const bf16x8_t*)&Vs[bc][r * 64 + (((kk * 4 + g) ^ (r & 7)) * 8)]; \
      _Pragma("unroll") for (int ni = 0; ni < 4; ++ni)                      \
        acc[ni] = __builtin_amdgcn_mfma_f32_16x16x32_bf16(af, bfg[ni][kk], acc[ni], 0, 0, 0); \
    }                                                                       \
    _Pragma("unroll") for (int ni = 0; ni < 4; ++ni)                        \
    _Pragma("unroll") for (int j = 0; j < 4; ++j)                           \
      ob[(size_t)((c_) * 64 + w * 16 + g * 4 + j) * HIDD + ni * 16 + fr] = f2bf(acc[ni][j]); \
  }

#define PWAIT(n_)                                                           \
  asm volatile("s_waitcnt vmcnt(" #n_ ")" ::: "memory");                    \
  __builtin_amdgcn_s_barrier();                                             \
  __builtin_amdgcn_sched_barrier(0);

  STGV(0, 0);
  STGV(1, 1);
  for (int c = 0; c < 6; ++c) {
    STGV((c + 2) % 3, c + 2);
    PWAIT(4);
    PCOMP(c % 3, c);
    __builtin_amdgcn_s_barrier();
  }
  PWAIT(2); PCOMP(0, 6); __builtin_amdgcn_s_barrier();
  PWAIT(0); PCOMP(1, 7);
#undef STGV
#undef PCOMP
#undef PWAIT
}

extern "C" void kernel_launch(void* const* d_in, const int* in_sizes, int n_in,
                              void* d_out, int out_size, void* d_ws, size_t ws_size,
                              hipStream_t stream) {
  const float* x = (const float*)d_in[0];
  const float* Wqkv = (const float*)d_in[1];
  const float* bqkv = (const float*)d_in[2];
  const float* Wz = (const float*)d_in[3];
  const float* bz = (const float*)d_in[4];
  const float* temperature = (const float*)d_in[5];

  char* ws = (char*)d_ws;
  ushort* xb    = (ushort*)(ws + 0);           // 33,554,432 (alias: attnout)
  ushort* wqb   = (ushort*)(ws + 33554432);    // 6,291,456
  ushort* wzb   = (ushort*)(ws + 39845888);    // 2,097,152
  ushort* vbuf  = (ushort*)(ws + 41943040);    // 33,554,432
  ushort* qkvT  = (ushort*)(ws + 75497472);    // 67,108,864  [t][b][h][d][s]
  ushort* attnout = xb;  // x is dead after QKV GEMM

  // scratch inside d_out (64 MB, fully overwritten by GEMM2 at the end):
  float* dsc = (float*)d_out;
  float* Wp8 = dsc;                        // 2,097,152 floats (8 MB)
  float* sq8 = dsc + 2097152;              // 32,768 floats
  float* sk8 = dsc + 2097152 + 32768;      // 32,768 floats
  ushort* attnb = (ushort*)(dsc + 2097152 + 65536);  // 294,912 ushorts

  // 1) fused converts (x|Wqkv|Wz -> contiguous bf16 region at ws+0)
  k_f2bf3<<<dim3(20480), dim3(256), 0, stream>>>(x, Wqkv, Wz, xb);

  // 2) QKV GEMM -> QT/KT transposed + V natural
  k_gemm8p<2, MM, NQKV, HIDD><<<dim3(MM / 256, NQKV / 256), dim3(512), 0, stream>>>(
      xb, wqb, bqkv, nullptr, qkvT, vbuf);

  // 3) gram eighths (+fused sumsq) -> combine+softmax
  k_gram<<<dim3(64, 8), dim3(256), 0, stream>>>(qkvT, Wp8, sq8, sk8);
  k_smx<<<dim3(64), dim3(256), 0, stream>>>(Wp8, sq8, sk8, temperature, attnb);

  // 4) PV (MFMA)
  k_pv<<<dim3(64, 8), dim3(256), 0, stream>>>(vbuf, attnb, attnout);

  // 5) output GEMM -> d_out fp32 (overwrites the scratch)
  k_gemm8p<1, MM, HIDD, HIDD><<<dim3(MM / 256, HIDD / 256), dim3(512), 0, stream>>>(
      attnout, wzb, bz, d_out, nullptr, nullptr);
}

// Round 14
// 208.785 us; speedup vs baseline: 1.1849x; 1.0053x over previous
//
#include <hip/hip_runtime.h>

#define DEVINL __device__ __forceinline__

// Problem constants
#define BB 4
#define SS 4096
#define HIDD 1024
#define HH 16
#define DH 64
#define NQKV 3072
#define MM (BB * SS)  // 16384

typedef __attribute__((ext_vector_type(8))) short bf16x8_t;
typedef __attribute__((ext_vector_type(4))) float f32x4_t;

typedef __attribute__((address_space(1))) const void GV;
typedef __attribute__((address_space(3))) void LV;

DEVINL void gload16(const void* g, void* l) {
  // async global->LDS, 16B/lane; LDS dest = wave-uniform base + lane*16
  __builtin_amdgcn_global_load_lds((GV*)g, (LV*)l, 16, 0, 0);
}

DEVINL float bf2f(ushort u) {
  union { unsigned int i; float f; } v;
  v.i = ((unsigned int)u) << 16;
  return v.f;
}
DEVINL ushort f2bf(float f) {
  unsigned int u = __float_as_uint(f);
  u = (u + 0x7fffu + ((u >> 16) & 1u)) >> 16;
  return (ushort)u;
}

// ------- fused fp32 -> bf16 convert for x|Wqkv|Wz (contiguous dst) -------
// dst ushort4 ranges: x [0,4194304), Wqkv [4194304,4980736), Wz [4980736,5242880)
__global__ __launch_bounds__(256) void k_f2bf3(const float* __restrict__ x,
                                               const float* __restrict__ wq,
                                               const float* __restrict__ wz,
                                               ushort* __restrict__ dst) {
  int i = blockIdx.x * 256 + threadIdx.x;
  const float* src;
  int off;
  if (i < 4194304) { src = x; off = i; }
  else if (i < 4980736) { src = wq; off = i - 4194304; }
  else { src = wz; off = i - 4980736; }
  float4 v = ((const float4*)src)[off];
  ushort4 o;
  o.x = f2bf(v.x); o.y = f2bf(v.y); o.z = f2bf(v.z); o.w = f2bf(v.w);
  ((ushort4*)dst)[i] = o;
}

// ---------------- 8-phase 256x256 bf16 GEMM, minimal-barrier schedule -------
// 8 waves (2M x 4N), BK=64, acc 8x4 frags of 16x16x32. 2 LDS K-tile slots per
// operand + dummy. 4 barriers/J (was 10):
//  - after ph1 MMA(1): all waves' LDB(Bs0) reads landed (own-lgkm before
//    MMA(0) + barrier) -> Bs0 overwritable at ph2/3.
//  - ph3 vmcnt(4)+bar: A(T1)/As1 complete (RAW) AND all waves' LDA(As0,*)
//    done (own-lgkm before MMA(3)) -> As0 overwritable at ph4/5.
//  - after ph5 / ph7: symmetric for Bs1 / As1.
// vmcnt math unchanged from the verified schedule (12 in flight -> drain 8).
// sched_barrier(0) only after the vmcnt fences (hoist there would race).
// MODE 2 Q/K epilogue: per-wave LDS-transposed stores -> 128B bursts along s.
template <int MODE, int MDIM, int NDIM, int KDIM>
__global__ __launch_bounds__(512, 2) void k_gemm8p(
    const ushort* __restrict__ A, const ushort* __restrict__ B,
    const float* __restrict__ bias, void* __restrict__ Cv,
    ushort* __restrict__ qT, ushort* __restrict__ vbuf) {
  __shared__ ushort As0[256 * 64];
  __shared__ ushort As1[256 * 64];
  __shared__ ushort Bs0[256 * 64];
  __shared__ ushort Bs1[256 * 64];
  __shared__ ushort Dmy[4096];
  constexpr int NT = KDIM >> 6;
  const int t = threadIdx.x;
  const int m0 = blockIdx.x * 256, n0 = blockIdx.y * 256;
  const int lane = t & 63, wid = t >> 6;
  const int wm = wid >> 2, wn = wid & 3;   // 2M x 4N waves
  const int fr = lane & 15, g = lane >> 4;
  const int srow = t >> 3;                        // 0..63 (row within 64-row call)
  const int schunk = ((t & 7) ^ (srow & 7)) * 8;  // pre-swizzled 16B chunk
  // per-thread staging bases (all further addressing is +constexpr)
  const ushort* Ab = A + (size_t)(m0 + srow) * KDIM + schunk;
  const ushort* Bb = B + (size_t)(n0 + srow) * KDIM + schunk;

  f32x4_t acc[8][4] = {};
  bf16x8_t af[2][2], bfr[4][2];

#define STG(ls_, gb_, tile, hf)                                             \
  {                                                                         \
    if ((tile) < NT) {                                                      \
      gload16((gb_) + (size_t)((hf) * 128) * KDIM + (tile) * 64,            \
              (ls_) + ((hf) * 128 + wid * 8) * 64);                         \
      gload16((gb_) + (size_t)((hf) * 128 + 64) * KDIM + (tile) * 64,       \
              (ls_) + ((hf) * 128 + wid * 8 + 64) * 64);                    \
    } else {                                                                \
      gload16((gb_), Dmy + wid * 512);                                      \
      gload16((gb_), Dmy + wid * 512);                                      \
    }                                                                       \
  }

#define LDA(as_, q)                                                         \
  _Pragma("unroll") for (int ii = 0; ii < 2; ++ii)                          \
  _Pragma("unroll") for (int kk = 0; kk < 2; ++kk) {                        \
    int r = wm * 128 + ((q) * 2 + ii) * 16 + fr;                            \
    af[ii][kk] = *(const bf16x8_t*)&(as_)[r * 64 + (((kk * 4 + g) ^ (r & 7)) * 8)]; \
  }

#define LDB(bs_)                                                            \
  _Pragma("unroll") for (int ni = 0; ni < 4; ++ni)                          \
  _Pragma("unroll") for (int kk = 0; kk < 2; ++kk) {                        \
    int r = wn * 64 + ni * 16 + fr;                                         \
    bfr[ni][kk] = *(const bf16x8_t*)&(bs_)[r * 64 + (((kk * 4 + g) ^ (r & 7)) * 8)]; \
  }

#define MMA(q)                                                              \
  _Pragma("unroll") for (int kk = 0; kk < 2; ++kk)                          \
  _Pragma("unroll") for (int ii = 0; ii < 2; ++ii)                          \
  _Pragma("unroll") for (int ni = 0; ni < 4; ++ni)                          \
    acc[(q) * 2 + ii][ni] = __builtin_amdgcn_mfma_f32_16x16x32_bf16(        \
        af[ii][kk], bfr[ni][kk], acc[(q) * 2 + ii][ni], 0, 0, 0);

#define MMAP(q)                                                             \
  __builtin_amdgcn_s_setprio(1);                                            \
  MMA(q);                                                                   \
  __builtin_amdgcn_s_setprio(0);

#define WARBAR                                                              \
  __builtin_amdgcn_s_barrier();

#define VMFENCE                                                             \
  asm volatile("s_waitcnt vmcnt(4)" ::: "memory");                          \
  __builtin_amdgcn_s_barrier();                                             \
  __builtin_amdgcn_sched_barrier(0);

  // prologue: B(0), A(0), B(1) fully staged; loop ph0/ph1 stage A(1).
  STG(Bs0, Bb, 0, 0); STG(Bs0, Bb, 0, 1);
  STG(As0, Ab, 0, 0); STG(As0, Ab, 0, 1);
  STG(Bs1, Bb, 1, 0); STG(Bs1, Bb, 1, 1);
  VMFENCE;

#pragma unroll
  for (int J = 0; J < (NT >> 1); ++J) {
    const int T0 = 2 * J, T1 = 2 * J + 1;
    // ph0-1 (no internal barrier; MFMA overlaps next phase's issue)
    LDA(As0, 0); LDB(Bs0); STG(As1, Ab, T1, 0);
    MMAP(0);
    LDA(As0, 1); STG(As1, Ab, T1, 1);
    MMAP(1);
    WARBAR;   // Bs0 free
    // ph2-3
    LDA(As0, 2); STG(Bs0, Bb, T0 + 2, 0);
    MMAP(2);
    LDA(As0, 3); STG(Bs0, Bb, T0 + 2, 1);
    MMAP(3);
    VMFENCE;  // As0 free; A(T1)->As1 complete
    // ph4-5
    LDA(As1, 0); LDB(Bs1); STG(As0, Ab, T0 + 2, 0);
    MMAP(0);
    LDA(As1, 1); STG(As0, Ab, T0 + 2, 1);
    MMAP(1);
    WARBAR;   // Bs1 free
    // ph6-7
    LDA(As1, 2); STG(Bs1, Bb, T1 + 2, 0);
    MMAP(2);
    LDA(As1, 3); STG(Bs1, Bb, T1 + 2, 1);
    MMAP(3);
    VMFENCE;  // As1 free; A(T0+2)->As0 + B(T0+2)->Bs0 complete
  }
#undef STG
#undef LDA
#undef LDB
#undef MMA
#undef MMAP
#undef WARBAR
#undef VMFENCE

  // ---- epilogue ----
  // reclaim LDS: all compute done; pending tail gloads target Dmy only.
  __syncthreads();

  if (MODE == 1) {
    // D col = lane&15, row = (lane>>4)*4 + reg (HW-verified mapping)
#pragma unroll
    for (int ni = 0; ni < 4; ++ni) {
      int col = n0 + wn * 64 + ni * 16 + fr;
      float bv = bias[col];
#pragma unroll
      for (int mi = 0; mi < 8; ++mi) {
        int rowbase = m0 + wm * 128 + mi * 16 + g * 4;
#pragma unroll
        for (int j = 0; j < 4; ++j)
          ((float*)Cv)[(size_t)(rowbase + j) * NDIM + col] = acc[mi][ni][j] + bv;
      }
    }
  } else {
    const int colbase = n0 + wn * 64;  // wave-uniform 64-col block
    if (colbase < 2048) {
      // Q/K: per-wave LDS transpose -> qT[tt][b][hh][d][s], 16B/lane along s.
      // wave scratch: 64 d-rows x stride 72 ushorts (16B-aligned rows).
      ushort* scr = (wid < 2 ? As0 : wid < 4 ? As1 : wid < 6 ? Bs0 : Bs1) +
                    (wid & 1) * 8192;
      const int tt = colbase >> 10;
      const int hh = (colbase >> 6) & 15;
      const int bb = m0 >> 12;
      const int sbase0 = (m0 & 4095) + wm * 128;
      const int ch = lane & 7, dq = lane >> 3;
      ushort* qbase = qT + (((size_t)tt * BB + bb) * HH + hh) * 64 * SS;
#pragma unroll
      for (int half = 0; half < 2; ++half) {
        // store acc -> scr[d = ni*16+fr][sl = mi_*16+g*4+j], pair-packed
#pragma unroll
        for (int ni = 0; ni < 4; ++ni) {
          float bv = bias[colbase + ni * 16 + fr];
#pragma unroll
          for (int mi_ = 0; mi_ < 4; ++mi_) {
#pragma unroll
            for (int jp = 0; jp < 2; ++jp) {
              unsigned int lo = f2bf(acc[half * 4 + mi_][ni][jp * 2] + bv);
              unsigned int hi = f2bf(acc[half * 4 + mi_][ni][jp * 2 + 1] + bv);
              *(unsigned int*)&scr[(ni * 16 + fr) * 72 + mi_ * 16 + g * 4 + jp * 2] =
                  lo | (hi << 16);
            }
          }
        }
        asm volatile("s_waitcnt lgkmcnt(0)" ::: "memory");
        // readback rows of 64 s-values, store 16B/lane contiguous in s
#pragma unroll
        for (int dr = 0; dr < 8; ++dr) {
          int d = dr * 8 + dq;
          int4 v = *(const int4*)&scr[d * 72 + ch * 8];
          *(int4*)&qbase[(size_t)d * SS + sbase0 + half * 64 + ch * 8] = v;
        }
        asm volatile("s_waitcnt lgkmcnt(0)" ::: "memory");
      }
    } else {
      // V: natural layout (32B bursts along c) — unchanged
#pragma unroll
      for (int ni = 0; ni < 4; ++ni) {
        int col = colbase + ni * 16 + fr;
        float bv = bias[col];
        int c = col - 2048;
#pragma unroll
        for (int mi = 0; mi < 8; ++mi) {
          int rowbase = m0 + wm * 128 + mi * 16 + g * 4;
          vbuf[(size_t)(rowbase + 0) * HIDD + c] = f2bf(acc[mi][ni][0] + bv);
          vbuf[(size_t)(rowbase + 1) * HIDD + c] = f2bf(acc[mi][ni][1] + bv);
          vbuf[(size_t)(rowbase + 2) * HIDD + c] = f2bf(acc[mi][ni][2] + bv);
          vbuf[(size_t)(rowbase + 3) * HIDD + c] = f2bf(acc[mi][ni][3] + bv);
        }
      }
    }
  }
}

// ------- gram eighth + fused sumsq partials -------
// grid (64 bh, 8 p): 512 s per block. 3-buffer counted-vmcnt staging.
// NO runtime-indexed register arrays (rule #20): K-row sumsq uses static ni
// with wave-uniform (ni == w) predicate.
// Partials to d_out scratch: Wp8[bh*8+p][64][64] f32, sq8/sk8[bh*8+p][64].
__global__ __launch_bounds__(256) void k_gram(const ushort* __restrict__ qT,
                                              float* __restrict__ Wp8,
                                              float* __restrict__ sq8,
                                              float* __restrict__ sk8) {
  __shared__ ushort Qs[3][64 * 64];
  __shared__ ushort Ks[3][64 * 64];
  const int bh = blockIdx.x, p = blockIdx.y;
  const ushort* Qp = qT + (size_t)bh * 64 * SS + p * 512;
  const ushort* Kp = qT + (size_t)(BB * HH + bh) * 64 * SS + p * 512;
  const int t = threadIdx.x;
  const int lane = t & 63, w = t >> 6;
  const int fr = lane & 15, g = lane >> 4;
  const int rsub = lane >> 3;
  const int gcol = ((lane & 7) ^ rsub) * 8;

  f32x4_t acc[4] = {};
  float sqa = 0.f, ska = 0.f;

#define STGG(b_, sc_)                                                       \
  _Pragma("unroll") for (int i = 0; i < 2; ++i) {                           \
    int rg = w * 2 + i;                                                     \
    int row = rg * 8 + rsub;                                                \
    gload16(&Qp[(size_t)row * SS + (sc_) * 64 + gcol], &Qs[b_][rg * 512]);  \
    gload16(&Kp[(size_t)row * SS + (sc_) * 64 + gcol], &Ks[b_][rg * 512]);  \
  }

#define GCOMP(bc)                                                           \
  {                                                                         \
    bf16x8_t af[2], bq[4][2];                                               \
    _Pragma("unroll") for (int kk = 0; kk < 2; ++kk) {                      \
      int r = w * 16 + fr;                                                  \
      af[kk] = *(const bf16x8_t*)&Qs[bc][r * 64 + (((kk * 4 + g) ^ (r & 7)) * 8)]; \
    }                                                                       \
    _Pragma("unroll") for (int ni = 0; ni < 4; ++ni)                        \
    _Pragma("unroll") for (int kk = 0; kk < 2; ++kk) {                      \
      int r2 = ni * 16 + fr;                                                \
      bq[ni][kk] = *(const bf16x8_t*)&Ks[bc][r2 * 64 + (((kk * 4 + g) ^ (r2 & 7)) * 8)]; \
    }                                                                       \
    _Pragma("unroll") for (int kk = 0; kk < 2; ++kk)                        \
    _Pragma("unroll") for (int ni = 0; ni < 4; ++ni)                        \
      acc[ni] = __builtin_amdgcn_mfma_f32_16x16x32_bf16(af[kk], bq[ni][kk], acc[ni], 0, 0, 0); \
    _Pragma("unroll") for (int kk = 0; kk < 2; ++kk)                        \
    _Pragma("unroll") for (int e = 0; e < 8; ++e) {                         \
      float fq = bf2f((ushort)af[kk][e]);                                   \
      sqa += fq * fq;                                                       \
    }                                                                       \
    _Pragma("unroll") for (int ni = 0; ni < 4; ++ni)                        \
      if (ni == w)                                                          \
        _Pragma("unroll") for (int kk = 0; kk < 2; ++kk)                    \
        _Pragma("unroll") for (int e = 0; e < 8; ++e) {                     \
          float fk = bf2f((ushort)bq[ni][kk][e]);                           \
          ska += fk * fk;                                                   \
        }                                                                   \
  }

#define GWAIT(n_)                                                           \
  asm volatile("s_waitcnt vmcnt(" #n_ ")" ::: "memory");                    \
  __builtin_amdgcn_s_barrier();                                             \
  __builtin_amdgcn_sched_barrier(0);

  STGG(0, 0);
  STGG(1, 1);
  for (int sc = 0; sc < 6; ++sc) {
    STGG((sc + 2) % 3, sc + 2);
    GWAIT(8);
    GCOMP(sc % 3);
    __builtin_amdgcn_s_barrier();
  }
  GWAIT(4); GCOMP(0); __builtin_amdgcn_s_barrier();  // sc=6 -> buf 0
  GWAIT(0); GCOMP(1);                                 // sc=7 -> buf 1
#undef STGG
#undef GCOMP
#undef GWAIT

  // reduce per-row sumsq over the 4 g-lanes; write partials
  sqa += __shfl_xor(sqa, 16, 64); sqa += __shfl_xor(sqa, 32, 64);
  ska += __shfl_xor(ska, 16, 64); ska += __shfl_xor(ska, 32, 64);
  const int bp = bh * 8 + p;
  if (g == 0) {
    sq8[bp * 64 + w * 16 + fr] = sqa;
    sk8[bp * 64 + w * 16 + fr] = ska;
  }
  float* wp = Wp8 + (size_t)bp * 4096;
#pragma unroll
  for (int ni = 0; ni < 4; ++ni)
#pragma unroll
    for (int j = 0; j < 4; ++j)
      wp[(w * 16 + g * 4 + j) * 64 + ni * 16 + fr] = acc[ni][j];
}

// ------- smx: combine partials, scale, softmax -> bf16 attnb[bh][64][72] ----
__global__ __launch_bounds__(256) void k_smx(const float* __restrict__ Wp8,
                                             const float* __restrict__ sq8,
                                             const float* __restrict__ sk8,
                                             const float* __restrict__ temperature,
                                             ushort* __restrict__ attnb) {
  __shared__ float attnf[64][65];
  __shared__ float iqL[64], ikL[64], invs[64];
  const int bh = blockIdx.x, h = bh & 15;
  const int t = threadIdx.x;
  if (t < 64) {
    float sq = 0.f, sk = 0.f;
#pragma unroll
    for (int p = 0; p < 8; ++p) {
      sq += sq8[(bh * 8 + p) * 64 + t];
      sk += sk8[(bh * 8 + p) * 64 + t];
    }
    iqL[t] = 1.0f / fmaxf(sqrtf(sq), 1e-12f);
    ikL[t] = 1.0f / fmaxf(sqrtf(sk), 1e-12f);
  }
  __syncthreads();
  float tscale = temperature[h] * (1.0f / 32.0f);
  for (int idx = t; idx < 4096; idx += 256) {
    int d = idx >> 6, e = idx & 63;
    float s = 0.f;
#pragma unroll
    for (int p = 0; p < 8; ++p) s += Wp8[(size_t)(bh * 8 + p) * 4096 + idx];
    attnf[d][e] = s * iqL[d] * ikL[e] * tscale;
  }
  __syncthreads();
  if (t < 64) {
    float m = -1e30f;
#pragma unroll 8
    for (int e = 0; e < 64; ++e) m = fmaxf(m, attnf[t][e]);
    float sum = 0.f;
#pragma unroll 8
    for (int e = 0; e < 64; ++e) {
      float v = __expf(attnf[t][e] - m);
      attnf[t][e] = v;
      sum += v;
    }
    invs[t] = 1.0f / sum;
  }
  __syncthreads();
  for (int idx = t; idx < 4096; idx += 256) {
    int d = idx >> 6, e = idx & 63;
    attnb[(size_t)bh * 4608 + d * 72 + e] = f2bf(attnf[d][e] * invs[d]);
  }
}

// ---------------- PV (MFMA): out[s][d] = sum_e V[s,e] * attn[d,e] ----------
// grid (64 bh, 8 p): 512 s-rows per block, 3-buffer counted-vmcnt staging.
__global__ __launch_bounds__(256) void k_pv(const ushort* __restrict__ vbuf,
                                            const ushort* __restrict__ attnb,
                                            ushort* __restrict__ attnout) {
  __shared__ ushort Vs[3][64 * 64];
  const int bh = blockIdx.x, p = blockIdx.y;
  const int b = bh >> 4, h = bh & 15;
  const int t = threadIdx.x;
  const int lane = t & 63, w = t >> 6;
  const int fr = lane & 15, g = lane >> 4;
  const int rsub = lane >> 3;
  const int gcol = ((lane & 7) ^ rsub) * 8;

  // B-frags straight from global attnb (L2-hot)
  bf16x8_t bfg[4][2];
#pragma unroll
  for (int ni = 0; ni < 4; ++ni)
#pragma unroll
    for (int kk = 0; kk < 2; ++kk)
      bfg[ni][kk] = *(const bf16x8_t*)&attnb[(size_t)bh * 4608 + (ni * 16 + fr) * 72 + (kk * 4 + g) * 8];

  const ushort* vb = vbuf + (size_t)(b * SS + p * 512) * HIDD + h * 64;
  ushort* ob = attnout + (size_t)(b * SS + p * 512) * HIDD + h * 64;

#define STGV(b_, c_)                                                        \
  _Pragma("unroll") for (int i = 0; i < 2; ++i) {                           \
    int rg = w * 2 + i;                                                     \
    int row = rg * 8 + rsub;                                                \
    gload16(&vb[(size_t)((c_) * 64 + row) * HIDD + gcol], &Vs[b_][rg * 512]); \
  }

#define PCOMP(bc, c_)                                                       \
  {                                                                         \
    f32x4_t acc[4] = {};                                                    \
    _Pragma("unroll") for (int kk = 0; kk < 2; ++kk) {                      \
      int r = w * 16 + fr;                                                  \
      bf16x8_t af = *(const bf16x8_t*)&Vs[bc][r * 64 + (((kk * 4 + g) ^ (r & 7)) * 8)]; \
      _Pragma("unroll") for (int ni = 0; ni < 4; ++ni)                      \
        acc[ni] = __builtin_amdgcn_mfma_f32_16x16x32_bf16(af, bfg[ni][kk], acc[ni], 0, 0, 0); \
    }                                                                       \
    _Pragma("unroll") for (int ni = 0; ni < 4; ++ni)                        \
    _Pragma("unroll") for (int j = 0; j < 4; ++j)                           \
      ob[(size_t)((c_) * 64 + w * 16 + g * 4 + j) * HIDD + ni * 16 + fr] = f2bf(acc[ni][j]); \
  }

#define PWAIT(n_)                                                           \
  asm volatile("s_waitcnt vmcnt(" #n_ ")" ::: "memory");                    \
  __builtin_amdgcn_s_barrier();                                             \
  __builtin_amdgcn_sched_barrier(0);

  STGV(0, 0);
  STGV(1, 1);
  for (int c = 0; c < 6; ++c) {
    STGV((c + 2) % 3, c + 2);
    PWAIT(4);
    PCOMP(c % 3, c);
    __builtin_amdgcn_s_barrier();
  }
  PWAIT(2); PCOMP(0, 6); __builtin_amdgcn_s_barrier();
  PWAIT(0); PCOMP(1, 7);
#undef STGV
#undef PCOMP
#undef PWAIT
}

extern "C" void kernel_launch(void* const* d_in, const int* in_sizes, int n_in,
                              void* d_out, int out_size, void* d_ws, size_t ws_size,
                              hipStream_t stream) {
  const float* x = (const float*)d_in[0];
  const float* Wqkv = (const float*)d_in[1];
  const float* bqkv = (const float*)d_in[2];
  const float* Wz = (const float*)d_in[3];
  const float* bz = (const float*)d_in[4];
  const float* temperature = (const float*)d_in[5];

  char* ws = (char*)d_ws;
  ushort* xb    = (ushort*)(ws + 0);           // 33,554,432 (alias: attnout)
  ushort* wqb   = (ushort*)(ws + 33554432);    // 6,291,456
  ushort* wzb   = (ushort*)(ws + 39845888);    // 2,097,152
  ushort* vbuf  = (ushort*)(ws + 41943040);    // 33,554,432
  ushort* qkvT  = (ushort*)(ws + 75497472);    // 67,108,864  [t][b][h][d][s]
  ushort* attnout = xb;  // x is dead after QKV GEMM

  // scratch inside d_out (64 MB, fully overwritten by GEMM2 at the end):
  float* dsc = (float*)d_out;
  float* Wp8 = dsc;                        // 2,097,152 floats (8 MB)
  float* sq8 = dsc + 2097152;              // 32,768 floats
  float* sk8 = dsc + 2097152 + 32768;      // 32,768 floats
  ushort* attnb = (ushort*)(dsc + 2097152 + 65536);  // 294,912 ushorts

  // 1) fused converts (x|Wqkv|Wz -> contiguous bf16 region at ws+0)
  k_f2bf3<<<dim3(20480), dim3(256), 0, stream>>>(x, Wqkv, Wz, xb);

  // 2) QKV GEMM -> QT/KT transposed + V natural
  k_gemm8p<2, MM, NQKV, HIDD><<<dim3(MM / 256, NQKV / 256), dim3(512), 0, stream>>>(
      xb, wqb, bqkv, nullptr, qkvT, vbuf);

  // 3) gram eighths (+fused sumsq) -> combine+softmax
  k_gram<<<dim3(64, 8), dim3(256), 0, stream>>>(qkvT, Wp8, sq8, sk8);
  k_smx<<<dim3(64), dim3(256), 0, stream>>>(Wp8, sq8, sk8, temperature, attnb);

  // 4) PV (MFMA)
  k_pv<<<dim3(64, 8), dim3(256), 0, stream>>>(vbuf, attnb, attnout);

  // 5) output GEMM -> d_out fp32 (overwrites the scratch)
  k_gemm8p<1, MM, HIDD, HIDD><<<dim3(MM / 256, HIDD / 256), dim3(512), 0, stream>>>(
      attnout, wzb, bz, d_out, nullptr, nullptr);
}